// Round 4
// baseline (229.052 us; speedup 1.0000x reference)
//
#include <hip/hip_runtime.h>
#include <math.h>

#define DMODEL 1024
#define DSTATE 16
#define DCONV 4
#define DINNER 2048
#define BATCH 2
#define SEQ 1024
#define BT (BATCH*SEQ)   // 2048
#define NC 16            // scan chunks
#define LC 64            // steps per chunk (NC*LC == SEQ)

typedef unsigned short ushort_t;
typedef __attribute__((ext_vector_type(8))) short short8;
typedef __attribute__((ext_vector_type(4))) float f32x4;

__device__ __forceinline__ ushort_t f2bf(float f) {
    union { float f; unsigned int u; } v; v.f = f;
    unsigned int r = v.u + 0x7fffu + ((v.u >> 16) & 1u);
    return (ushort_t)(r >> 16);
}

__device__ __forceinline__ float softplusf(float x) {
    return (x > 20.f) ? x : log1pf(__expf(x));
}

#define GLOAD_LDS16(G, L) \
  __builtin_amdgcn_global_load_lds((const __attribute__((address_space(1))) void*)(G), \
                                   (__attribute__((address_space(3))) void*)(L), 16, 0, 0)

// ---------------------------------------------------------------------------
__global__ __launch_bounds__(256) void zero_kernel(float* __restrict__ p)
{
    size_t i = ((size_t)blockIdx.x * 256 + threadIdx.x) * 4;
    *(float4*)&p[i] = make_float4(0.f, 0.f, 0.f, 0.f);
}

// ---------------------------------------------------------------------------
__global__ __launch_bounds__(256) void cast_bf16_kernel(const float* __restrict__ in,
                                                        ushort_t* __restrict__ out)
{
    size_t i = ((size_t)blockIdx.x * 256 + threadIdx.x) * 8;
    float4 a = *(const float4*)&in[i];
    float4 b = *(const float4*)&in[i + 4];
    uint4 p;
    p.x = (unsigned)f2bf(a.x) | ((unsigned)f2bf(a.y) << 16);
    p.y = (unsigned)f2bf(a.z) | ((unsigned)f2bf(a.w) << 16);
    p.z = (unsigned)f2bf(b.x) | ((unsigned)f2bf(b.y) << 16);
    p.w = (unsigned)f2bf(b.z) | ((unsigned)f2bf(b.w) << 16);
    *(uint4*)&out[i] = p;
}

// ---------------------------------------------------------------------------
__global__ __launch_bounds__(256) void transpose_cast_kernel(const float* __restrict__ in,
                                                             ushort_t* __restrict__ out,
                                                             int R, int Cc)
{
    __shared__ float t[32][33];
    const int r0 = blockIdx.y * 32;
    const int c0 = blockIdx.x * 32;
    const int tid = threadIdx.x;
    {
        int lr = tid >> 3, lc4 = (tid & 7) * 4;
        float4 v = *(const float4*)&in[(size_t)(r0 + lr) * Cc + c0 + lc4];
        t[lr][lc4 + 0] = v.x; t[lr][lc4 + 1] = v.y;
        t[lr][lc4 + 2] = v.z; t[lr][lc4 + 3] = v.w;
    }
    __syncthreads();
    {
        int oc = tid >> 3, rq = (tid & 7) * 4;
        ushort4 u;
        u.x = f2bf(t[rq + 0][oc]);
        u.y = f2bf(t[rq + 1][oc]);
        u.z = f2bf(t[rq + 2][oc]);
        u.w = f2bf(t[rq + 3][oc]);
        *(ushort4*)&out[(size_t)(c0 + oc) * R + r0 + rq] = u;
    }
}

// ---------------------------------------------------------------------------
// bf16 MFMA GEMM: C[M][N] (fp32) = A[M][K] @ Bt[N][K]^T.
// ---------------------------------------------------------------------------
template<int BM, int BN>
__global__ __launch_bounds__(256) void gemm_bt(const ushort_t* __restrict__ A,
                                               const ushort_t* __restrict__ Bt,
                                               float* __restrict__ C,
                                               int M, int N, int K)
{
    constexpr int BK = 32;
    constexpr int AL = BM * BK / (256 * 8);
    constexpr int BL = BN * BK / (256 * 8);
    constexpr int FM = BM / 32;
    constexpr int FN = BN / 32;
    __shared__ __align__(16) ushort_t Al[BM * BK];
    __shared__ __align__(16) ushort_t Bl[BN * BK];

    const int tid  = threadIdx.x;
    const int lane = tid & 63;
    const int wid  = tid >> 6;
    const int wr   = wid >> 1;
    const int wc   = wid & 1;
    const int bm   = blockIdx.y * BM;
    const int bn   = blockIdx.x * BN;

    f32x4 acc[FM][FN] = {};

    for (int k0 = 0; k0 < K; k0 += BK) {
#pragma unroll
        for (int j = 0; j < AL; j++) {
            int chunk = j * 256 + tid;
            GLOAD_LDS16(&A[(size_t)(bm + (chunk >> 2)) * K + k0 + (chunk & 3) * 8],
                        &Al[(size_t)(j * 256 + wid * 64) * 8]);
        }
#pragma unroll
        for (int j = 0; j < BL; j++) {
            int chunk = j * 256 + tid;
            GLOAD_LDS16(&Bt[(size_t)(bn + (chunk >> 2)) * K + k0 + (chunk & 3) * 8],
                        &Bl[(size_t)(j * 256 + wid * 64) * 8]);
        }
        __syncthreads();

        short8 af[FM], bf[FN];
#pragma unroll
        for (int m = 0; m < FM; m++)
            af[m] = *(const short8*)&Al[(wr * (BM / 2) + m * 16 + (lane & 15)) * BK + (lane >> 4) * 8];
#pragma unroll
        for (int n = 0; n < FN; n++)
            bf[n] = *(const short8*)&Bl[(wc * (BN / 2) + n * 16 + (lane & 15)) * BK + (lane >> 4) * 8];
#pragma unroll
        for (int m = 0; m < FM; m++)
#pragma unroll
            for (int n = 0; n < FN; n++)
                acc[m][n] = __builtin_amdgcn_mfma_f32_16x16x32_bf16(af[m], bf[n], acc[m][n], 0, 0, 0);
        __syncthreads();
    }

#pragma unroll
    for (int m = 0; m < FM; m++)
#pragma unroll
        for (int n = 0; n < FN; n++) {
            int row0 = bm + wr * (BM / 2) + m * 16 + (lane >> 4) * 4;
            int col  = bn + wc * (BN / 2) + n * 16 + (lane & 15);
#pragma unroll
            for (int r = 0; r < 4; r++)
                C[(size_t)(row0 + r) * N + col] = acc[m][n][r];
        }
}

// ---------------------------------------------------------------------------
// Depthwise causal conv(4) + bias + SiLU, row-major out.
// ---------------------------------------------------------------------------
__global__ __launch_bounds__(256) void conv_silu_kernel(const float* __restrict__ xz,
                                                        const float* __restrict__ cw,
                                                        const float* __restrict__ cb,
                                                        float* __restrict__ xb_rm)
{
    __shared__ float tile[64 + 3][64];
    const int b  = blockIdx.z;
    const int t0 = blockIdx.x * 64;
    const int d0 = blockIdx.y * 64;
    const int tid = threadIdx.x;

    for (int e = tid; e < 67 * 16; e += 256) {
        int r  = e / 16;
        int c4 = (e % 16) * 4;
        int t  = t0 - 3 + r;
        float4 v = make_float4(0.f, 0.f, 0.f, 0.f);
        if (t >= 0)
            v = *(const float4*)&xz[((size_t)b * SEQ + t) * (2 * DINNER) + d0 + c4];
        *(float4*)&tile[r][c4] = v;
    }
    __syncthreads();

    const int dl = tid & 63;
    const int tb = tid >> 6;
    const int d  = d0 + dl;
    const float w0 = cw[d * 4 + 0], w1 = cw[d * 4 + 1];
    const float w2 = cw[d * 4 + 2], w3 = cw[d * 4 + 3];
    const float bias = cb[d];

#pragma unroll
    for (int ii = 0; ii < 16; ii++) {
        int tl = tb + 4 * ii;
        float s = bias;
        s = fmaf(tile[tl + 0][dl], w0, s);
        s = fmaf(tile[tl + 1][dl], w1, s);
        s = fmaf(tile[tl + 2][dl], w2, s);
        s = fmaf(tile[tl + 3][dl], w3, s);
        float sil = s / (1.f + __expf(-s));
        xb_rm[((size_t)b * SEQ + t0 + tl) * DINNER + d] = sil;
    }
}

// ---------------------------------------------------------------------------
// xproj split-K: grid (BT/8, 8); stages xs + ws in LDS; atomics out.
// ---------------------------------------------------------------------------
__global__ __launch_bounds__(256) void xproj_kernel(const float* __restrict__ xb,
                                                    const float* __restrict__ w,
                                                    float* __restrict__ Btb,
                                                    float* __restrict__ Ctb,
                                                    float* __restrict__ dtraw)
{
    __shared__ float xs[8][256];
    __shared__ float ws[256][33];
    const int bt0 = blockIdx.x * 8;
    const int kc  = blockIdx.y * 256;
    const int tid = threadIdx.x;
    const int r = tid >> 5, n = tid & 31;

#pragma unroll
    for (int j = 0; j < 2; j++) {
        int e4 = (j * 256 + tid) * 4;
        int rr = e4 >> 8, cc = e4 & 255;
        *(float4*)&xs[rr][cc] = *(const float4*)&xb[(size_t)(bt0 + rr) * DINNER + kc + cc];
    }
    {
        const float* wsrc = w + (size_t)kc * 33;
        float* wdst = &ws[0][0];
        for (int e4 = tid; e4 < 2112; e4 += 256)
            *(float4*)&wdst[e4 * 4] = *(const float4*)&wsrc[e4 * 4];
    }
    __syncthreads();

    float acc = 0.f;
#pragma unroll 16
    for (int kk = 0; kk < 256; kk += 4) {
        float4 xv = *(const float4*)&xs[r][kk];
        acc = fmaf(xv.x, ws[kk + 0][n], acc);
        acc = fmaf(xv.y, ws[kk + 1][n], acc);
        acc = fmaf(xv.z, ws[kk + 2][n], acc);
        acc = fmaf(xv.w, ws[kk + 3][n], acc);
    }
    float dacc = 0.f;
#pragma unroll
    for (int j = 0; j < 8; j++)
        dacc = fmaf(xs[r][n * 8 + j], ws[n * 8 + j][32], dacc);
#pragma unroll
    for (int off = 16; off; off >>= 1)
        dacc += __shfl_xor(dacc, off, 32);

    if (n < 16) atomicAdd(&Btb[(bt0 + r) * 16 + n], acc);
    else        atomicAdd(&Ctb[(bt0 + r) * 16 + (n - 16)], acc);
    if (n == 0) atomicAdd(&dtraw[bt0 + r], dacc);
}

// ---------------------------------------------------------------------------
// scan1: per-chunk local scan (h0=0). Lane = (d-group g, state s).
// grid (NC, DINNER/16, BATCH), 256 threads. LDS-staged dt/x/B tiles.
// Writes Hend[b][c][d][s] and dtsum[b][c][d].
// ---------------------------------------------------------------------------
__global__ __launch_bounds__(256) void scan1_kernel(const float* __restrict__ xb,
                                                    const float* __restrict__ dtraw,
                                                    const float* __restrict__ Btb,
                                                    const float* __restrict__ A_log,
                                                    const float* __restrict__ dtw,
                                                    const float* __restrict__ dtb,
                                                    float* __restrict__ Hend,
                                                    float* __restrict__ dtsum)
{
    __shared__ float raw[LC];
    __shared__ float dts[LC][16];
    __shared__ float xs[LC][16];
    __shared__ float Bs[LC][16];

    const int tid   = threadIdx.x;
    const int s     = tid & 15;
    const int g     = tid >> 4;
    const int c     = blockIdx.x;
    const int dtile = blockIdx.y;
    const int b     = blockIdx.z;
    const int d0    = dtile * 16;
    const int d     = d0 + g;
    const int t0    = c * LC;

    if (tid < LC / 4)
        *(float4*)&raw[tid * 4] = *(const float4*)&dtraw[b * SEQ + t0 + tid * 4];

    {   // xs, Bs: 64 rows x 16 cols, each row 64B = 4 float4; thread (row=tid>>2, col4=tid&3)
        int rr = tid >> 2, c4 = (tid & 3) * 4;
        *(float4*)&xs[rr][c4] = *(const float4*)&xb[((size_t)b * SEQ + t0 + rr) * DINNER + d0 + c4];
        *(float4*)&Bs[rr][c4] = *(const float4*)&Btb[((size_t)b * SEQ + t0 + rr) * 16 + c4];
    }
    __syncthreads();
    {   // dts[i][g2] = softplus(raw[i]*w+b); thread covers 4 entries
        int i = tid & 63, g2 = tid >> 6;
        float w0 = dtw[d0 + g2 * 4], b0 = dtb[d0 + g2 * 4];
        float w1 = dtw[d0 + g2 * 4 + 1], b1 = dtb[d0 + g2 * 4 + 1];
        float w2 = dtw[d0 + g2 * 4 + 2], b2 = dtb[d0 + g2 * 4 + 2];
        float w3 = dtw[d0 + g2 * 4 + 3], b3 = dtb[d0 + g2 * 4 + 3];
        float rv = raw[i];
        dts[i][g2 * 4 + 0] = softplusf(fmaf(rv, w0, b0));
        dts[i][g2 * 4 + 1] = softplusf(fmaf(rv, w1, b1));
        dts[i][g2 * 4 + 2] = softplusf(fmaf(rv, w2, b2));
        dts[i][g2 * 4 + 3] = softplusf(fmaf(rv, w3, b3));
    }
    __syncthreads();

    const float As2 = -__expf(A_log[d * 16 + s]) * 1.44269504f;
    float h = 0.f, dsum = 0.f;
#pragma unroll 4
    for (int i = 0; i < LC; i++) {
        float dt = dts[i][g];
        float a  = exp2f(dt * As2);
        h = fmaf(a, h, dt * xs[i][g] * Bs[i][s]);
        dsum += dt;
    }
    size_t base = (((size_t)b * NC + c) * 128 + dtile) * 256;
    Hend[base + tid] = h;
    if (s == 0) dtsum[((size_t)b * NC + c) * DINNER + d] = dsum;
}

// ---------------------------------------------------------------------------
// carry: thread per (b,d,s); walk NC chunks; Hstart[c] = running state.
// ---------------------------------------------------------------------------
__global__ __launch_bounds__(256) void carry_kernel(const float* __restrict__ Hend,
                                                    const float* __restrict__ dtsum,
                                                    const float* __restrict__ A_log,
                                                    float* __restrict__ Hstart)
{
    const int idx = blockIdx.x * 256 + threadIdx.x;   // (b,d,s)
    const int s = idx & 15;
    const int d = (idx >> 4) & (DINNER - 1);
    const int b = idx >> 15;
    const float As2 = -__expf(A_log[d * 16 + s]) * 1.44269504f;
    float hs = 0.f;
    for (int c = 0; c < NC; c++) {
        size_t off = ((size_t)b * NC + c);
        float P  = exp2f(As2 * dtsum[off * DINNER + d]);
        size_t hi = (off * DINNER + d) * 16 + s;
        float he = Hend[hi];
        Hstart[hi] = hs;
        hs = fmaf(P, hs, he);
    }
}

// ---------------------------------------------------------------------------
// scan3: recompute with true h_start; y-dot via shfl; fused gate epilogue
// writes bf16 ygb directly.
// ---------------------------------------------------------------------------
__global__ __launch_bounds__(256) void scan3_kernel(const float* __restrict__ xb,
                                                    const float* __restrict__ dtraw,
                                                    const float* __restrict__ Btb,
                                                    const float* __restrict__ Ctb,
                                                    const float* __restrict__ A_log,
                                                    const float* __restrict__ dtw,
                                                    const float* __restrict__ dtb,
                                                    const float* __restrict__ Hstart,
                                                    const float* __restrict__ xz,
                                                    const float* __restrict__ Dp,
                                                    ushort_t* __restrict__ ygb)
{
    __shared__ float raw[LC];
    __shared__ float dts[LC][16];
    __shared__ float xs[LC][16];
    __shared__ float Bs[LC][16];
    __shared__ float Cs[LC][16];
    __shared__ float ys[LC][16];

    const int tid   = threadIdx.x;
    const int s     = tid & 15;
    const int g     = tid >> 4;
    const int c     = blockIdx.x;
    const int dtile = blockIdx.y;
    const int b     = blockIdx.z;
    const int d0    = dtile * 16;
    const int d     = d0 + g;
    const int t0    = c * LC;

    if (tid < LC / 4)
        *(float4*)&raw[tid * 4] = *(const float4*)&dtraw[b * SEQ + t0 + tid * 4];
    {
        int rr = tid >> 2, c4 = (tid & 3) * 4;
        *(float4*)&xs[rr][c4] = *(const float4*)&xb[((size_t)b * SEQ + t0 + rr) * DINNER + d0 + c4];
        *(float4*)&Bs[rr][c4] = *(const float4*)&Btb[((size_t)b * SEQ + t0 + rr) * 16 + c4];
        *(float4*)&Cs[rr][c4] = *(const float4*)&Ctb[((size_t)b * SEQ + t0 + rr) * 16 + c4];
    }
    __syncthreads();
    {
        int i = tid & 63, g2 = tid >> 6;
        float w0 = dtw[d0 + g2 * 4], b0 = dtb[d0 + g2 * 4];
        float w1 = dtw[d0 + g2 * 4 + 1], b1 = dtb[d0 + g2 * 4 + 1];
        float w2 = dtw[d0 + g2 * 4 + 2], b2 = dtb[d0 + g2 * 4 + 2];
        float w3 = dtw[d0 + g2 * 4 + 3], b3 = dtb[d0 + g2 * 4 + 3];
        float rv = raw[i];
        dts[i][g2 * 4 + 0] = softplusf(fmaf(rv, w0, b0));
        dts[i][g2 * 4 + 1] = softplusf(fmaf(rv, w1, b1));
        dts[i][g2 * 4 + 2] = softplusf(fmaf(rv, w2, b2));
        dts[i][g2 * 4 + 3] = softplusf(fmaf(rv, w3, b3));
    }

    const float As2 = -__expf(A_log[d * 16 + s]) * 1.44269504f;
    float h = Hstart[(((size_t)b * NC + c) * 128 + dtile) * 256 + tid];
    __syncthreads();

#pragma unroll 4
    for (int i = 0; i < LC; i++) {
        float dt = dts[i][g];
        float a  = exp2f(dt * As2);
        h = fmaf(a, h, dt * xs[i][g] * Bs[i][s]);
        float p = h * Cs[i][s];
        p += __shfl_xor(p, 1, 16);
        p += __shfl_xor(p, 2, 16);
        p += __shfl_xor(p, 4, 16);
        p += __shfl_xor(p, 8, 16);
        if (s == 0) ys[i][g] = p;
    }
    __syncthreads();

    // fused gate epilogue: out = (y + D*x) * silu(z), bf16
    {
        int rr = tid >> 2, c4 = (tid & 3) * 4;
        float4 yv = *(const float4*)&ys[rr][c4];
        float4 xv = *(const float4*)&xs[rr][c4];
        float4 zv = *(const float4*)&xz[((size_t)b * SEQ + t0 + rr) * (2 * DINNER) + DINNER + d0 + c4];
        float4 dv = *(const float4*)&Dp[d0 + c4];
        ushort4 u;
        u.x = f2bf(fmaf(dv.x, xv.x, yv.x) * (zv.x / (1.f + __expf(-zv.x))));
        u.y = f2bf(fmaf(dv.y, xv.y, yv.y) * (zv.y / (1.f + __expf(-zv.y))));
        u.z = f2bf(fmaf(dv.z, xv.z, yv.z) * (zv.z / (1.f + __expf(-zv.z))));
        u.w = f2bf(fmaf(dv.w, xv.w, yv.w) * (zv.w / (1.f + __expf(-zv.w))));
        *(ushort4*)&ygb[((size_t)b * SEQ + t0 + rr) * DINNER + d0 + c4] = u;
    }
}

// ---------------------------------------------------------------------------
extern "C" void kernel_launch(void* const* d_in, const int* in_sizes, int n_in,
                              void* d_out, int out_size, void* d_ws, size_t ws_size,
                              hipStream_t stream)
{
    const float* x         = (const float*)d_in[0];
    const float* in_proj_w = (const float*)d_in[1];
    const float* conv_w    = (const float*)d_in[2];
    const float* conv_b    = (const float*)d_in[3];
    const float* x_proj_w  = (const float*)d_in[4];
    const float* dt_proj_w = (const float*)d_in[5];
    const float* dt_proj_b = (const float*)d_in[6];
    const float* A_log     = (const float*)d_in[7];
    const float* D_param   = (const float*)d_in[8];
    const float* c_proj_w  = (const float*)d_in[9];
    float* out = (float*)d_out;

    float* ws    = (float*)d_ws;
    float* xz    = ws;                                   // BT*4096 f32
    float* xb    = xz  + (size_t)BT * 4096;              // BT*2048 f32
    float* Btb   = xb  + (size_t)BT * DINNER;            // BT*16
    float* Ctb   = Btb + (size_t)BT * 16;                // BT*16
    float* dtraw = Ctb + (size_t)BT * 16;                // BT (B,C,dt contiguous BT*33)
    float* Hend  = dtraw + BT;                           // B*NC*D*S = 1M f32
    float* Hstart= Hend + (size_t)BATCH * NC * DINNER * 16;
    float* dtsum = Hstart + (size_t)BATCH * NC * DINNER * 16; // B*NC*D
    ushort_t* xbf = (ushort_t*)(dtsum + (size_t)BATCH * NC * DINNER);
    ushort_t* w1T = xbf + (size_t)BT * DMODEL;           // 4096*1024 bf16
    ushort_t* w2T = w1T + (size_t)(2 * DINNER) * DMODEL; // 1024*2048 bf16
    ushort_t* ygb = w2T + (size_t)DMODEL * DINNER;       // BT*2048 bf16

    // zero B/C/dtraw accumulators (BT*33 = 67584 floats)
    zero_kernel<<<dim3(66), 256, 0, stream>>>(Btb);

    cast_bf16_kernel<<<dim3((BT * DMODEL) / (8 * 256)), 256, 0, stream>>>(x, xbf);
    transpose_cast_kernel<<<dim3((2 * DINNER) / 32, DMODEL / 32), 256, 0, stream>>>(
        in_proj_w, w1T, DMODEL, 2 * DINNER);
    transpose_cast_kernel<<<dim3(DMODEL / 32, DINNER / 32), 256, 0, stream>>>(
        c_proj_w, w2T, DINNER, DMODEL);

    // 1. xz = x @ in_proj_w (bf16 MFMA)
    gemm_bt<128, 128><<<dim3((2 * DINNER) / 128, BT / 128), 256, 0, stream>>>(
        xbf, w1T, xz, BT, 2 * DINNER, DMODEL);

    // 2. conv + bias + silu
    conv_silu_kernel<<<dim3(SEQ / 64, DINNER / 64, BATCH), 256, 0, stream>>>(
        xz, conv_w, conv_b, xb);

    // 3. x_ssm projection (split-K atomics)
    xproj_kernel<<<dim3(BT / 8, 8), 256, 0, stream>>>(xb, x_proj_w, Btb, Ctb, dtraw);

    // 4. chunked scan: local -> carry -> final(+fused gate, bf16 out)
    scan1_kernel<<<dim3(NC, DINNER / 16, BATCH), 256, 0, stream>>>(
        xb, dtraw, Btb, A_log, dt_proj_w, dt_proj_b, Hend, dtsum);
    carry_kernel<<<dim3(BATCH * DINNER * 16 / 256), 256, 0, stream>>>(
        Hend, dtsum, A_log, Hstart);
    scan3_kernel<<<dim3(NC, DINNER / 16, BATCH), 256, 0, stream>>>(
        xb, dtraw, Btb, Ctb, A_log, dt_proj_w, dt_proj_b, Hstart, xz, D_param, ygb);

    // 5. out = y @ c_proj_w (bf16 MFMA)
    gemm_bt<64, 128><<<dim3(DMODEL / 128, BT / 64), 256, 0, stream>>>(
        ygb, w2T, out, BT, DMODEL, DINNER);
}

// Round 5
// 193.692 us; speedup vs baseline: 1.1826x; 1.1826x over previous
//
#include <hip/hip_runtime.h>
#include <math.h>

#define DMODEL 1024
#define DSTATE 16
#define DCONV 4
#define DINNER 2048
#define BATCH 2
#define SEQ 1024
#define BT (BATCH*SEQ)   // 2048
#define NC 16            // scan chunks
#define LC 64            // steps per chunk (NC*LC == SEQ)

typedef unsigned short ushort_t;
typedef __attribute__((ext_vector_type(8))) short short8;
typedef __attribute__((ext_vector_type(4))) float f32x4;

__device__ __forceinline__ ushort_t f2bf(float f) {
    union { float f; unsigned int u; } v; v.f = f;
    unsigned int r = v.u + 0x7fffu + ((v.u >> 16) & 1u);
    return (ushort_t)(r >> 16);
}

__device__ __forceinline__ float softplusf(float x) {
    return (x > 20.f) ? x : log1pf(__expf(x));
}

#define GLOAD_LDS16(G, L) \
  __builtin_amdgcn_global_load_lds((const __attribute__((address_space(1))) void*)(G), \
                                   (__attribute__((address_space(3))) void*)(L), 16, 0, 0)

// ---------------------------------------------------------------------------
__global__ __launch_bounds__(256) void zero_kernel(float* __restrict__ p)
{
    size_t i = ((size_t)blockIdx.x * 256 + threadIdx.x) * 4;
    *(float4*)&p[i] = make_float4(0.f, 0.f, 0.f, 0.f);
}

// ---------------------------------------------------------------------------
__global__ __launch_bounds__(256) void cast_bf16_kernel(const float* __restrict__ in,
                                                        ushort_t* __restrict__ out)
{
    size_t i = ((size_t)blockIdx.x * 256 + threadIdx.x) * 8;
    float4 a = *(const float4*)&in[i];
    float4 b = *(const float4*)&in[i + 4];
    uint4 p;
    p.x = (unsigned)f2bf(a.x) | ((unsigned)f2bf(a.y) << 16);
    p.y = (unsigned)f2bf(a.z) | ((unsigned)f2bf(a.w) << 16);
    p.z = (unsigned)f2bf(b.x) | ((unsigned)f2bf(b.y) << 16);
    p.w = (unsigned)f2bf(b.z) | ((unsigned)f2bf(b.w) << 16);
    *(uint4*)&out[i] = p;
}

// ---------------------------------------------------------------------------
__global__ __launch_bounds__(256) void transpose_cast_kernel(const float* __restrict__ in,
                                                             ushort_t* __restrict__ out,
                                                             int R, int Cc)
{
    __shared__ float t[32][33];
    const int r0 = blockIdx.y * 32;
    const int c0 = blockIdx.x * 32;
    const int tid = threadIdx.x;
    {
        int lr = tid >> 3, lc4 = (tid & 7) * 4;
        float4 v = *(const float4*)&in[(size_t)(r0 + lr) * Cc + c0 + lc4];
        t[lr][lc4 + 0] = v.x; t[lr][lc4 + 1] = v.y;
        t[lr][lc4 + 2] = v.z; t[lr][lc4 + 3] = v.w;
    }
    __syncthreads();
    {
        int oc = tid >> 3, rq = (tid & 7) * 4;
        ushort4 u;
        u.x = f2bf(t[rq + 0][oc]);
        u.y = f2bf(t[rq + 1][oc]);
        u.z = f2bf(t[rq + 2][oc]);
        u.w = f2bf(t[rq + 3][oc]);
        *(ushort4*)&out[(size_t)(c0 + oc) * R + r0 + rq] = u;
    }
}

// ---------------------------------------------------------------------------
// bf16 MFMA GEMM: C[M][N] (fp32) = A[M][K] @ Bt[N][K]^T.
// ---------------------------------------------------------------------------
template<int BM, int BN>
__global__ __launch_bounds__(256) void gemm_bt(const ushort_t* __restrict__ A,
                                               const ushort_t* __restrict__ Bt,
                                               float* __restrict__ C,
                                               int M, int N, int K)
{
    constexpr int BK = 32;
    constexpr int AL = BM * BK / (256 * 8);
    constexpr int BL = BN * BK / (256 * 8);
    constexpr int FM = BM / 32;
    constexpr int FN = BN / 32;
    __shared__ __align__(16) ushort_t Al[BM * BK];
    __shared__ __align__(16) ushort_t Bl[BN * BK];

    const int tid  = threadIdx.x;
    const int lane = tid & 63;
    const int wid  = tid >> 6;
    const int wr   = wid >> 1;
    const int wc   = wid & 1;
    const int bm   = blockIdx.y * BM;
    const int bn   = blockIdx.x * BN;

    f32x4 acc[FM][FN] = {};

    for (int k0 = 0; k0 < K; k0 += BK) {
#pragma unroll
        for (int j = 0; j < AL; j++) {
            int chunk = j * 256 + tid;
            GLOAD_LDS16(&A[(size_t)(bm + (chunk >> 2)) * K + k0 + (chunk & 3) * 8],
                        &Al[(size_t)(j * 256 + wid * 64) * 8]);
        }
#pragma unroll
        for (int j = 0; j < BL; j++) {
            int chunk = j * 256 + tid;
            GLOAD_LDS16(&Bt[(size_t)(bn + (chunk >> 2)) * K + k0 + (chunk & 3) * 8],
                        &Bl[(size_t)(j * 256 + wid * 64) * 8]);
        }
        __syncthreads();

        short8 af[FM], bf[FN];
#pragma unroll
        for (int m = 0; m < FM; m++)
            af[m] = *(const short8*)&Al[(wr * (BM / 2) + m * 16 + (lane & 15)) * BK + (lane >> 4) * 8];
#pragma unroll
        for (int n = 0; n < FN; n++)
            bf[n] = *(const short8*)&Bl[(wc * (BN / 2) + n * 16 + (lane & 15)) * BK + (lane >> 4) * 8];
#pragma unroll
        for (int m = 0; m < FM; m++)
#pragma unroll
            for (int n = 0; n < FN; n++)
                acc[m][n] = __builtin_amdgcn_mfma_f32_16x16x32_bf16(af[m], bf[n], acc[m][n], 0, 0, 0);
        __syncthreads();
    }

#pragma unroll
    for (int m = 0; m < FM; m++)
#pragma unroll
        for (int n = 0; n < FN; n++) {
            int row0 = bm + wr * (BM / 2) + m * 16 + (lane >> 4) * 4;
            int col  = bn + wc * (BN / 2) + n * 16 + (lane & 15);
#pragma unroll
            for (int r = 0; r < 4; r++)
                C[(size_t)(row0 + r) * N + col] = acc[m][n][r];
        }
}

// ---------------------------------------------------------------------------
// Depthwise causal conv(4) + bias + SiLU, row-major out.
// ---------------------------------------------------------------------------
__global__ __launch_bounds__(256) void conv_silu_kernel(const float* __restrict__ xz,
                                                        const float* __restrict__ cw,
                                                        const float* __restrict__ cb,
                                                        float* __restrict__ xb_rm)
{
    __shared__ float tile[64 + 3][64];
    const int b  = blockIdx.z;
    const int t0 = blockIdx.x * 64;
    const int d0 = blockIdx.y * 64;
    const int tid = threadIdx.x;

    for (int e = tid; e < 67 * 16; e += 256) {
        int r  = e / 16;
        int c4 = (e % 16) * 4;
        int t  = t0 - 3 + r;
        float4 v = make_float4(0.f, 0.f, 0.f, 0.f);
        if (t >= 0)
            v = *(const float4*)&xz[((size_t)b * SEQ + t) * (2 * DINNER) + d0 + c4];
        *(float4*)&tile[r][c4] = v;
    }
    __syncthreads();

    const int dl = tid & 63;
    const int tb = tid >> 6;
    const int d  = d0 + dl;
    const float w0 = cw[d * 4 + 0], w1 = cw[d * 4 + 1];
    const float w2 = cw[d * 4 + 2], w3 = cw[d * 4 + 3];
    const float bias = cb[d];

#pragma unroll
    for (int ii = 0; ii < 16; ii++) {
        int tl = tb + 4 * ii;
        float s = bias;
        s = fmaf(tile[tl + 0][dl], w0, s);
        s = fmaf(tile[tl + 1][dl], w1, s);
        s = fmaf(tile[tl + 2][dl], w2, s);
        s = fmaf(tile[tl + 3][dl], w3, s);
        float sil = s / (1.f + __expf(-s));
        xb_rm[((size_t)b * SEQ + t0 + tl) * DINNER + d] = sil;
    }
}

// ---------------------------------------------------------------------------
// xproj split-K: grid (BT/8, 8); stages xs + ws in LDS; atomics out.
// ---------------------------------------------------------------------------
__global__ __launch_bounds__(256) void xproj_kernel(const float* __restrict__ xb,
                                                    const float* __restrict__ w,
                                                    float* __restrict__ Btb,
                                                    float* __restrict__ Ctb,
                                                    float* __restrict__ dtraw)
{
    __shared__ float xs[8][256];
    __shared__ float ws[256][33];
    const int bt0 = blockIdx.x * 8;
    const int kc  = blockIdx.y * 256;
    const int tid = threadIdx.x;
    const int r = tid >> 5, n = tid & 31;

#pragma unroll
    for (int j = 0; j < 2; j++) {
        int e4 = (j * 256 + tid) * 4;
        int rr = e4 >> 8, cc = e4 & 255;
        *(float4*)&xs[rr][cc] = *(const float4*)&xb[(size_t)(bt0 + rr) * DINNER + kc + cc];
    }
    {
        const float* wsrc = w + (size_t)kc * 33;
        float* wdst = &ws[0][0];
        for (int e4 = tid; e4 < 2112; e4 += 256)
            *(float4*)&wdst[e4 * 4] = *(const float4*)&wsrc[e4 * 4];
    }
    __syncthreads();

    float acc = 0.f;
#pragma unroll 16
    for (int kk = 0; kk < 256; kk += 4) {
        float4 xv = *(const float4*)&xs[r][kk];
        acc = fmaf(xv.x, ws[kk + 0][n], acc);
        acc = fmaf(xv.y, ws[kk + 1][n], acc);
        acc = fmaf(xv.z, ws[kk + 2][n], acc);
        acc = fmaf(xv.w, ws[kk + 3][n], acc);
    }
    float dacc = 0.f;
#pragma unroll
    for (int j = 0; j < 8; j++)
        dacc = fmaf(xs[r][n * 8 + j], ws[n * 8 + j][32], dacc);
#pragma unroll
    for (int off = 16; off; off >>= 1)
        dacc += __shfl_xor(dacc, off, 32);

    if (n < 16) atomicAdd(&Btb[(bt0 + r) * 16 + n], acc);
    else        atomicAdd(&Ctb[(bt0 + r) * 16 + (n - 16)], acc);
    if (n == 0) atomicAdd(&dtraw[bt0 + r], dacc);
}

// ---------------------------------------------------------------------------
// scan1: per-chunk local scan (h0=0). Lane = (d-group g, state s).
// Writes Hend[b][c][d][s] and dtsum[b][c][d].
// ---------------------------------------------------------------------------
__global__ __launch_bounds__(256) void scan1_kernel(const float* __restrict__ xb,
                                                    const float* __restrict__ dtraw,
                                                    const float* __restrict__ Btb,
                                                    const float* __restrict__ A_log,
                                                    const float* __restrict__ dtw,
                                                    const float* __restrict__ dtb,
                                                    float* __restrict__ Hend,
                                                    float* __restrict__ dtsum)
{
    __shared__ float raw[LC];
    __shared__ float dts[LC][16];
    __shared__ float xs[LC][16];
    __shared__ float Bs[LC][16];

    const int tid   = threadIdx.x;
    const int s     = tid & 15;
    const int g     = tid >> 4;
    const int c     = blockIdx.x;
    const int dtile = blockIdx.y;
    const int b     = blockIdx.z;
    const int d0    = dtile * 16;
    const int d     = d0 + g;
    const int t0    = c * LC;

    if (tid < LC / 4)
        *(float4*)&raw[tid * 4] = *(const float4*)&dtraw[b * SEQ + t0 + tid * 4];

    {
        int rr = tid >> 2, c4 = (tid & 3) * 4;
        *(float4*)&xs[rr][c4] = *(const float4*)&xb[((size_t)b * SEQ + t0 + rr) * DINNER + d0 + c4];
        *(float4*)&Bs[rr][c4] = *(const float4*)&Btb[((size_t)b * SEQ + t0 + rr) * 16 + c4];
    }
    __syncthreads();
    {
        int i = tid & 63, g2 = tid >> 6;
        float w0 = dtw[d0 + g2 * 4], b0 = dtb[d0 + g2 * 4];
        float w1 = dtw[d0 + g2 * 4 + 1], b1 = dtb[d0 + g2 * 4 + 1];
        float w2 = dtw[d0 + g2 * 4 + 2], b2 = dtb[d0 + g2 * 4 + 2];
        float w3 = dtw[d0 + g2 * 4 + 3], b3 = dtb[d0 + g2 * 4 + 3];
        float rv = raw[i];
        dts[i][g2 * 4 + 0] = softplusf(fmaf(rv, w0, b0));
        dts[i][g2 * 4 + 1] = softplusf(fmaf(rv, w1, b1));
        dts[i][g2 * 4 + 2] = softplusf(fmaf(rv, w2, b2));
        dts[i][g2 * 4 + 3] = softplusf(fmaf(rv, w3, b3));
    }
    __syncthreads();

    const float As2 = -__expf(A_log[d * 16 + s]) * 1.44269504f;
    float h = 0.f, dsum = 0.f;
#pragma unroll 4
    for (int i = 0; i < LC; i++) {
        float dt = dts[i][g];
        float a  = exp2f(dt * As2);
        h = fmaf(a, h, dt * xs[i][g] * Bs[i][s]);
        dsum += dt;
    }
    size_t base = (((size_t)b * NC + c) * 128 + dtile) * 256;
    Hend[base + tid] = h;
    if (s == 0) dtsum[((size_t)b * NC + c) * DINNER + d] = dsum;
}

// ---------------------------------------------------------------------------
// carry: thread per (b,d,s); walk NC chunks; Hstart[c] = running state.
// ---------------------------------------------------------------------------
__global__ __launch_bounds__(256) void carry_kernel(const float* __restrict__ Hend,
                                                    const float* __restrict__ dtsum,
                                                    const float* __restrict__ A_log,
                                                    float* __restrict__ Hstart)
{
    const int idx = blockIdx.x * 256 + threadIdx.x;   // (b,d,s)
    const int s = idx & 15;
    const int d = (idx >> 4) & (DINNER - 1);
    const int b = idx >> 15;
    const float As2 = -__expf(A_log[d * 16 + s]) * 1.44269504f;
    float hs = 0.f;
    for (int c = 0; c < NC; c++) {
        size_t off = ((size_t)b * NC + c);
        float P  = exp2f(As2 * dtsum[off * DINNER + d]);
        size_t hi = (off * DINNER + d) * 16 + s;
        float he = Hend[hi];
        Hstart[hi] = hs;
        hs = fmaf(P, hs, he);
    }
}

// ---------------------------------------------------------------------------
// scan3 v2: recompute with true h_start. y-dot via LDS stage + balanced
// reduce pass every 16 steps (no cross-lane shuffles on the critical path).
// Fused gate epilogue writes bf16 ygb.
// ---------------------------------------------------------------------------
__global__ __launch_bounds__(256) void scan3_kernel(const float* __restrict__ xb,
                                                    const float* __restrict__ dtraw,
                                                    const float* __restrict__ Btb,
                                                    const float* __restrict__ Ctb,
                                                    const float* __restrict__ A_log,
                                                    const float* __restrict__ dtw,
                                                    const float* __restrict__ dtb,
                                                    const float* __restrict__ Hstart,
                                                    const float* __restrict__ xz,
                                                    const float* __restrict__ Dp,
                                                    ushort_t* __restrict__ ygb)
{
    __shared__ float raw[LC];
    __shared__ float dts[LC][16];
    __shared__ float xs[LC][16];
    __shared__ float Bs[LC][16];
    __shared__ float Cs[LC][16];
    __shared__ float ysc[16][260];   // per-sub-chunk h*C terms, padded row
    __shared__ float ys[LC][16];     // reduced y

    const int tid   = threadIdx.x;
    const int s     = tid & 15;
    const int g     = tid >> 4;
    const int c     = blockIdx.x;
    const int dtile = blockIdx.y;
    const int b     = blockIdx.z;
    const int d0    = dtile * 16;
    const int d     = d0 + g;
    const int t0    = c * LC;

    if (tid < LC / 4)
        *(float4*)&raw[tid * 4] = *(const float4*)&dtraw[b * SEQ + t0 + tid * 4];
    {
        int rr = tid >> 2, c4 = (tid & 3) * 4;
        *(float4*)&xs[rr][c4] = *(const float4*)&xb[((size_t)b * SEQ + t0 + rr) * DINNER + d0 + c4];
        *(float4*)&Bs[rr][c4] = *(const float4*)&Btb[((size_t)b * SEQ + t0 + rr) * 16 + c4];
        *(float4*)&Cs[rr][c4] = *(const float4*)&Ctb[((size_t)b * SEQ + t0 + rr) * 16 + c4];
    }
    __syncthreads();
    {
        int i = tid & 63, g2 = tid >> 6;
        float w0 = dtw[d0 + g2 * 4], b0 = dtb[d0 + g2 * 4];
        float w1 = dtw[d0 + g2 * 4 + 1], b1 = dtb[d0 + g2 * 4 + 1];
        float w2 = dtw[d0 + g2 * 4 + 2], b2 = dtb[d0 + g2 * 4 + 2];
        float w3 = dtw[d0 + g2 * 4 + 3], b3 = dtb[d0 + g2 * 4 + 3];
        float rv = raw[i];
        dts[i][g2 * 4 + 0] = softplusf(fmaf(rv, w0, b0));
        dts[i][g2 * 4 + 1] = softplusf(fmaf(rv, w1, b1));
        dts[i][g2 * 4 + 2] = softplusf(fmaf(rv, w2, b2));
        dts[i][g2 * 4 + 3] = softplusf(fmaf(rv, w3, b3));
    }

    const float As2 = -__expf(A_log[d * 16 + s]) * 1.44269504f;
    float h = Hstart[(((size_t)b * NC + c) * 128 + dtile) * 256 + tid];
    __syncthreads();

    const int rg = tid >> 4;   // reduce role: sub-chunk step
    const int rd = tid & 15;   // reduce role: d
    for (int ii = 0; ii < LC; ii += 16) {
#pragma unroll
        for (int i2 = 0; i2 < 16; i2++) {
            const int i = ii + i2;
            float dt = dts[i][g];
            float a  = exp2f(dt * As2);
            h = fmaf(a, h, dt * xs[i][g] * Bs[i][s]);
            ysc[i2][tid] = h * Cs[i][s];
        }
        __syncthreads();
        {
            float4 p0 = *(const float4*)&ysc[rg][rd * 16 + 0];
            float4 p1 = *(const float4*)&ysc[rg][rd * 16 + 4];
            float4 p2 = *(const float4*)&ysc[rg][rd * 16 + 8];
            float4 p3 = *(const float4*)&ysc[rg][rd * 16 + 12];
            float t1 = ((p0.x + p0.y) + (p0.z + p0.w)) + ((p1.x + p1.y) + (p1.z + p1.w));
            float t2 = ((p2.x + p2.y) + (p2.z + p2.w)) + ((p3.x + p3.y) + (p3.z + p3.w));
            ys[ii + rg][rd] = t1 + t2;
        }
        __syncthreads();
    }

    // fused gate epilogue: out = (y + D*x) * silu(z), bf16
    {
        int rr = tid >> 2, c4 = (tid & 3) * 4;
        float4 yv = *(const float4*)&ys[rr][c4];
        float4 xv = *(const float4*)&xs[rr][c4];
        float4 zv = *(const float4*)&xz[((size_t)b * SEQ + t0 + rr) * (2 * DINNER) + DINNER + d0 + c4];
        float4 dv = *(const float4*)&Dp[d0 + c4];
        ushort4 u;
        u.x = f2bf(fmaf(dv.x, xv.x, yv.x) * (zv.x / (1.f + __expf(-zv.x))));
        u.y = f2bf(fmaf(dv.y, xv.y, yv.y) * (zv.y / (1.f + __expf(-zv.y))));
        u.z = f2bf(fmaf(dv.z, xv.z, yv.z) * (zv.z / (1.f + __expf(-zv.z))));
        u.w = f2bf(fmaf(dv.w, xv.w, yv.w) * (zv.w / (1.f + __expf(-zv.w))));
        *(ushort4*)&ygb[((size_t)b * SEQ + t0 + rr) * DINNER + d0 + c4] = u;
    }
}

// ---------------------------------------------------------------------------
extern "C" void kernel_launch(void* const* d_in, const int* in_sizes, int n_in,
                              void* d_out, int out_size, void* d_ws, size_t ws_size,
                              hipStream_t stream)
{
    const float* x         = (const float*)d_in[0];
    const float* in_proj_w = (const float*)d_in[1];
    const float* conv_w    = (const float*)d_in[2];
    const float* conv_b    = (const float*)d_in[3];
    const float* x_proj_w  = (const float*)d_in[4];
    const float* dt_proj_w = (const float*)d_in[5];
    const float* dt_proj_b = (const float*)d_in[6];
    const float* A_log     = (const float*)d_in[7];
    const float* D_param   = (const float*)d_in[8];
    const float* c_proj_w  = (const float*)d_in[9];
    float* out = (float*)d_out;

    float* ws    = (float*)d_ws;
    float* xz    = ws;                                   // BT*4096 f32
    float* xb    = xz  + (size_t)BT * 4096;              // BT*2048 f32
    float* Btb   = xb  + (size_t)BT * DINNER;            // BT*16
    float* Ctb   = Btb + (size_t)BT * 16;                // BT*16
    float* dtraw = Ctb + (size_t)BT * 16;                // BT (B,C,dt contiguous BT*33)
    float* Hend  = dtraw + BT;                           // B*NC*D*S = 1M f32
    float* Hstart= Hend + (size_t)BATCH * NC * DINNER * 16;
    float* dtsum = Hstart + (size_t)BATCH * NC * DINNER * 16; // B*NC*D
    ushort_t* xbf = (ushort_t*)(dtsum + (size_t)BATCH * NC * DINNER);
    ushort_t* w1T = xbf + (size_t)BT * DMODEL;           // 4096*1024 bf16
    ushort_t* w2T = w1T + (size_t)(2 * DINNER) * DMODEL; // 1024*2048 bf16
    ushort_t* ygb = w2T + (size_t)DMODEL * DINNER;       // BT*2048 bf16

    // zero B/C/dtraw accumulators (BT*33 = 67584 floats)
    zero_kernel<<<dim3(66), 256, 0, stream>>>(Btb);

    cast_bf16_kernel<<<dim3((BT * DMODEL) / (8 * 256)), 256, 0, stream>>>(x, xbf);
    transpose_cast_kernel<<<dim3((2 * DINNER) / 32, DMODEL / 32), 256, 0, stream>>>(
        in_proj_w, w1T, DMODEL, 2 * DINNER);
    transpose_cast_kernel<<<dim3(DMODEL / 32, DINNER / 32), 256, 0, stream>>>(
        c_proj_w, w2T, DINNER, DMODEL);

    // 1. xz = x @ in_proj_w (bf16 MFMA)
    gemm_bt<128, 128><<<dim3((2 * DINNER) / 128, BT / 128), 256, 0, stream>>>(
        xbf, w1T, xz, BT, 2 * DINNER, DMODEL);

    // 2. conv + bias + silu
    conv_silu_kernel<<<dim3(SEQ / 64, DINNER / 64, BATCH), 256, 0, stream>>>(
        xz, conv_w, conv_b, xb);

    // 3. x_ssm projection (split-K atomics)
    xproj_kernel<<<dim3(BT / 8, 8), 256, 0, stream>>>(xb, x_proj_w, Btb, Ctb, dtraw);

    // 4. chunked scan: local -> carry -> final(+fused gate, bf16 out)
    scan1_kernel<<<dim3(NC, DINNER / 16, BATCH), 256, 0, stream>>>(
        xb, dtraw, Btb, A_log, dt_proj_w, dt_proj_b, Hend, dtsum);
    carry_kernel<<<dim3(BATCH * DINNER * 16 / 256), 256, 0, stream>>>(
        Hend, dtsum, A_log, Hstart);
    scan3_kernel<<<dim3(NC, DINNER / 16, BATCH), 256, 0, stream>>>(
        xb, dtraw, Btb, Ctb, A_log, dt_proj_w, dt_proj_b, Hstart, xz, D_param, ygb);

    // 5. out = y @ c_proj_w (bf16 MFMA)
    gemm_bt<64, 128><<<dim3(DMODEL / 128, BT / 64), 256, 0, stream>>>(
        ygb, w2T, out, BT, DMODEL, DINNER);
}

// Round 6
// 175.825 us; speedup vs baseline: 1.3027x; 1.1016x over previous
//
#include <hip/hip_runtime.h>
#include <math.h>

#define DMODEL 1024
#define DSTATE 16
#define DCONV 4
#define DINNER 2048
#define BATCH 2
#define SEQ 1024
#define BT (BATCH*SEQ)   // 2048
#define NC 32            // scan chunks
#define LC 32            // steps per chunk (NC*LC == SEQ)

typedef unsigned short ushort_t;
typedef __attribute__((ext_vector_type(8))) short short8;
typedef __attribute__((ext_vector_type(4))) float f32x4;

__device__ __forceinline__ ushort_t f2bf(float f) {
    union { float f; unsigned int u; } v; v.f = f;
    unsigned int r = v.u + 0x7fffu + ((v.u >> 16) & 1u);
    return (ushort_t)(r >> 16);
}

__device__ __forceinline__ float softplusf(float x) {
    return (x > 20.f) ? x : log1pf(__expf(x));
}

#define GLOAD_LDS16(G, L) \
  __builtin_amdgcn_global_load_lds((const __attribute__((address_space(1))) void*)(G), \
                                   (__attribute__((address_space(3))) void*)(L), 16, 0, 0)

// ---------------------------------------------------------------------------
__global__ __launch_bounds__(256) void zero_kernel(float* __restrict__ p)
{
    size_t i = ((size_t)blockIdx.x * 256 + threadIdx.x) * 4;
    *(float4*)&p[i] = make_float4(0.f, 0.f, 0.f, 0.f);
}

// ---------------------------------------------------------------------------
__global__ __launch_bounds__(256) void cast_bf16_kernel(const float* __restrict__ in,
                                                        ushort_t* __restrict__ out)
{
    size_t i = ((size_t)blockIdx.x * 256 + threadIdx.x) * 8;
    float4 a = *(const float4*)&in[i];
    float4 b = *(const float4*)&in[i + 4];
    uint4 p;
    p.x = (unsigned)f2bf(a.x) | ((unsigned)f2bf(a.y) << 16);
    p.y = (unsigned)f2bf(a.z) | ((unsigned)f2bf(a.w) << 16);
    p.z = (unsigned)f2bf(b.x) | ((unsigned)f2bf(b.y) << 16);
    p.w = (unsigned)f2bf(b.z) | ((unsigned)f2bf(b.w) << 16);
    *(uint4*)&out[i] = p;
}

// ---------------------------------------------------------------------------
__global__ __launch_bounds__(256) void transpose_cast_kernel(const float* __restrict__ in,
                                                             ushort_t* __restrict__ out,
                                                             int R, int Cc)
{
    __shared__ float t[32][33];
    const int r0 = blockIdx.y * 32;
    const int c0 = blockIdx.x * 32;
    const int tid = threadIdx.x;
    {
        int lr = tid >> 3, lc4 = (tid & 7) * 4;
        float4 v = *(const float4*)&in[(size_t)(r0 + lr) * Cc + c0 + lc4];
        t[lr][lc4 + 0] = v.x; t[lr][lc4 + 1] = v.y;
        t[lr][lc4 + 2] = v.z; t[lr][lc4 + 3] = v.w;
    }
    __syncthreads();
    {
        int oc = tid >> 3, rq = (tid & 7) * 4;
        ushort4 u;
        u.x = f2bf(t[rq + 0][oc]);
        u.y = f2bf(t[rq + 1][oc]);
        u.z = f2bf(t[rq + 2][oc]);
        u.w = f2bf(t[rq + 3][oc]);
        *(ushort4*)&out[(size_t)(c0 + oc) * R + r0 + rq] = u;
    }
}

// ---------------------------------------------------------------------------
// bf16 MFMA GEMM: C[M][N] (fp32) = A[M][K] @ Bt[N][K]^T.
// ---------------------------------------------------------------------------
template<int BM, int BN>
__global__ __launch_bounds__(256) void gemm_bt(const ushort_t* __restrict__ A,
                                               const ushort_t* __restrict__ Bt,
                                               float* __restrict__ C,
                                               int M, int N, int K)
{
    constexpr int BK = 32;
    constexpr int AL = BM * BK / (256 * 8);
    constexpr int BL = BN * BK / (256 * 8);
    constexpr int FM = BM / 32;
    constexpr int FN = BN / 32;
    __shared__ __align__(16) ushort_t Al[BM * BK];
    __shared__ __align__(16) ushort_t Bl[BN * BK];

    const int tid  = threadIdx.x;
    const int lane = tid & 63;
    const int wid  = tid >> 6;
    const int wr   = wid >> 1;
    const int wc   = wid & 1;
    const int bm   = blockIdx.y * BM;
    const int bn   = blockIdx.x * BN;

    f32x4 acc[FM][FN] = {};

    for (int k0 = 0; k0 < K; k0 += BK) {
#pragma unroll
        for (int j = 0; j < AL; j++) {
            int chunk = j * 256 + tid;
            GLOAD_LDS16(&A[(size_t)(bm + (chunk >> 2)) * K + k0 + (chunk & 3) * 8],
                        &Al[(size_t)(j * 256 + wid * 64) * 8]);
        }
#pragma unroll
        for (int j = 0; j < BL; j++) {
            int chunk = j * 256 + tid;
            GLOAD_LDS16(&Bt[(size_t)(bn + (chunk >> 2)) * K + k0 + (chunk & 3) * 8],
                        &Bl[(size_t)(j * 256 + wid * 64) * 8]);
        }
        __syncthreads();

        short8 af[FM], bf[FN];
#pragma unroll
        for (int m = 0; m < FM; m++)
            af[m] = *(const short8*)&Al[(wr * (BM / 2) + m * 16 + (lane & 15)) * BK + (lane >> 4) * 8];
#pragma unroll
        for (int n = 0; n < FN; n++)
            bf[n] = *(const short8*)&Bl[(wc * (BN / 2) + n * 16 + (lane & 15)) * BK + (lane >> 4) * 8];
#pragma unroll
        for (int m = 0; m < FM; m++)
#pragma unroll
            for (int n = 0; n < FN; n++)
                acc[m][n] = __builtin_amdgcn_mfma_f32_16x16x32_bf16(af[m], bf[n], acc[m][n], 0, 0, 0);
        __syncthreads();
    }

#pragma unroll
    for (int m = 0; m < FM; m++)
#pragma unroll
        for (int n = 0; n < FN; n++) {
            int row0 = bm + wr * (BM / 2) + m * 16 + (lane >> 4) * 4;
            int col  = bn + wc * (BN / 2) + n * 16 + (lane & 15);
#pragma unroll
            for (int r = 0; r < 4; r++)
                C[(size_t)(row0 + r) * N + col] = acc[m][n][r];
        }
}

// ---------------------------------------------------------------------------
// Depthwise causal conv(4) + bias + SiLU, row-major out.
// ---------------------------------------------------------------------------
__global__ __launch_bounds__(256) void conv_silu_kernel(const float* __restrict__ xz,
                                                        const float* __restrict__ cw,
                                                        const float* __restrict__ cb,
                                                        float* __restrict__ xb_rm)
{
    __shared__ float tile[64 + 3][64];
    const int b  = blockIdx.z;
    const int t0 = blockIdx.x * 64;
    const int d0 = blockIdx.y * 64;
    const int tid = threadIdx.x;

    for (int e = tid; e < 67 * 16; e += 256) {
        int r  = e / 16;
        int c4 = (e % 16) * 4;
        int t  = t0 - 3 + r;
        float4 v = make_float4(0.f, 0.f, 0.f, 0.f);
        if (t >= 0)
            v = *(const float4*)&xz[((size_t)b * SEQ + t) * (2 * DINNER) + d0 + c4];
        *(float4*)&tile[r][c4] = v;
    }
    __syncthreads();

    const int dl = tid & 63;
    const int tb = tid >> 6;
    const int d  = d0 + dl;
    const float w0 = cw[d * 4 + 0], w1 = cw[d * 4 + 1];
    const float w2 = cw[d * 4 + 2], w3 = cw[d * 4 + 3];
    const float bias = cb[d];

#pragma unroll
    for (int ii = 0; ii < 16; ii++) {
        int tl = tb + 4 * ii;
        float s = bias;
        s = fmaf(tile[tl + 0][dl], w0, s);
        s = fmaf(tile[tl + 1][dl], w1, s);
        s = fmaf(tile[tl + 2][dl], w2, s);
        s = fmaf(tile[tl + 3][dl], w3, s);
        float sil = s / (1.f + __expf(-s));
        xb_rm[((size_t)b * SEQ + t0 + tl) * DINNER + d] = sil;
    }
}

// ---------------------------------------------------------------------------
// xproj split-K: grid (BT/8, 8); stages xs + ws in LDS; atomics out.
// ---------------------------------------------------------------------------
__global__ __launch_bounds__(256) void xproj_kernel(const float* __restrict__ xb,
                                                    const float* __restrict__ w,
                                                    float* __restrict__ Btb,
                                                    float* __restrict__ Ctb,
                                                    float* __restrict__ dtraw)
{
    __shared__ float xs[8][256];
    __shared__ float ws[256][33];
    const int bt0 = blockIdx.x * 8;
    const int kc  = blockIdx.y * 256;
    const int tid = threadIdx.x;
    const int r = tid >> 5, n = tid & 31;

#pragma unroll
    for (int j = 0; j < 2; j++) {
        int e4 = (j * 256 + tid) * 4;
        int rr = e4 >> 8, cc = e4 & 255;
        *(float4*)&xs[rr][cc] = *(const float4*)&xb[(size_t)(bt0 + rr) * DINNER + kc + cc];
    }
    {
        const float* wsrc = w + (size_t)kc * 33;
        float* wdst = &ws[0][0];
        for (int e4 = tid; e4 < 2112; e4 += 256)
            *(float4*)&wdst[e4 * 4] = *(const float4*)&wsrc[e4 * 4];
    }
    __syncthreads();

    float acc = 0.f;
#pragma unroll 16
    for (int kk = 0; kk < 256; kk += 4) {
        float4 xv = *(const float4*)&xs[r][kk];
        acc = fmaf(xv.x, ws[kk + 0][n], acc);
        acc = fmaf(xv.y, ws[kk + 1][n], acc);
        acc = fmaf(xv.z, ws[kk + 2][n], acc);
        acc = fmaf(xv.w, ws[kk + 3][n], acc);
    }
    float dacc = 0.f;
#pragma unroll
    for (int j = 0; j < 8; j++)
        dacc = fmaf(xs[r][n * 8 + j], ws[n * 8 + j][32], dacc);
#pragma unroll
    for (int off = 16; off; off >>= 1)
        dacc += __shfl_xor(dacc, off, 32);

    if (n < 16) atomicAdd(&Btb[(bt0 + r) * 16 + n], acc);
    else        atomicAdd(&Ctb[(bt0 + r) * 16 + (n - 16)], acc);
    if (n == 0) atomicAdd(&dtraw[bt0 + r], dacc);
}

// ---------------------------------------------------------------------------
// Power-tree: a[s] = q^(s+1) for s=0..15 (binary decomposition, depth ~4).
// ---------------------------------------------------------------------------
__device__ __forceinline__ void qpowers(float q, float* a)
{
    float q2 = q * q, q4 = q2 * q2, q8 = q4 * q4;
    a[0] = q;        a[1] = q2;       a[2] = q2 * q;   a[3] = q4;
    a[4] = q4 * q;   a[5] = q4 * q2;  a[6] = q4 * a[2];a[7] = q8;
    a[8] = q8 * q;   a[9] = q8 * q2;  a[10]= q8 * a[2];a[11]= q8 * q4;
    a[12]= q8 * a[4];a[13]= q8 * a[5];a[14]= q8 * a[6];a[15]= q8 * q8;
}

// Check A_log[d][s] == log(s+1)*... i.e. As2[s] == (s+1)*As2[0] (fast path).
__device__ __forceinline__ bool a_structure_ok(const float* A_log, int d, float As2_0)
{
    bool ok = true;
#pragma unroll
    for (int s = 1; s < 16; s++) {
        float v = -__expf(A_log[d * 16 + s]) * 1.44269504f;
        ok &= (fabsf(v - (float)(s + 1) * As2_0) <= 1e-4f * (float)(s + 1) * fabsf(As2_0));
    }
    return ok;
}

// ---------------------------------------------------------------------------
// scan1: thread-per-d. Block = 256 d x one chunk of LC=32 steps.
// grid (NC, DINNER/256, BATCH). h[16] in registers, B rows broadcast from LDS.
// Writes Hend[b][c][d][16], dtsum[b][c][d].
// ---------------------------------------------------------------------------
__global__ __launch_bounds__(256) void scan1_kernel(const float* __restrict__ xb,
                                                    const float* __restrict__ dtraw,
                                                    const float* __restrict__ Btb,
                                                    const float* __restrict__ A_log,
                                                    const float* __restrict__ dtw,
                                                    const float* __restrict__ dtb,
                                                    float* __restrict__ Hend,
                                                    float* __restrict__ dtsum)
{
    __shared__ float raw[LC];
    __shared__ float xs[LC][256];
    __shared__ float Bs[LC][16];

    const int tid = threadIdx.x;
    const int c   = blockIdx.x;
    const int b   = blockIdx.z;
    const int d0  = blockIdx.y * 256;
    const int d   = d0 + tid;
    const int t0  = c * LC;

    if (tid < LC / 4)
        *(float4*)&raw[tid * 4] = *(const float4*)&dtraw[b * SEQ + t0 + tid * 4];
    if (tid < 128)
        *(float4*)&Bs[0][tid * 4] = *(const float4*)&Btb[((size_t)b * SEQ + t0) * 16 + tid * 4];
#pragma unroll
    for (int j = 0; j < 8; j++) {
        int e = j * 256 + tid;
        int rr = e >> 6, c4 = (e & 63) * 4;
        *(float4*)&xs[rr][c4] = *(const float4*)&xb[((size_t)b * SEQ + t0 + rr) * DINNER + d0 + c4];
    }

    const float wd = dtw[d], bd = dtb[d];
    const float As2_0 = -__expf(A_log[d * 16]) * 1.44269504f;
    const bool fast = a_structure_ok(A_log, d, As2_0);

    float h[16];
#pragma unroll
    for (int s = 0; s < 16; s++) h[s] = 0.f;
    float dsum = 0.f;
    __syncthreads();

    if (fast) {
#pragma unroll 2
        for (int t = 0; t < LC; t++) {
            float dt = softplusf(fmaf(raw[t], wd, bd));
            float xv = xs[t][tid];
            float Bv[16];
#pragma unroll
            for (int s4 = 0; s4 < 4; s4++)
                *(float4*)&Bv[s4 * 4] = *(const float4*)&Bs[t][s4 * 4];
            float a[16];
            qpowers(exp2f(dt * As2_0), a);
            float dtx = dt * xv;
            dsum += dt;
#pragma unroll
            for (int s = 0; s < 16; s++)
                h[s] = fmaf(a[s], h[s], Bv[s] * dtx);
        }
    } else {
        float As2[16];
#pragma unroll
        for (int s = 0; s < 16; s++)
            As2[s] = -__expf(A_log[d * 16 + s]) * 1.44269504f;
#pragma unroll 2
        for (int t = 0; t < LC; t++) {
            float dt = softplusf(fmaf(raw[t], wd, bd));
            float xv = xs[t][tid];
            float Bv[16];
#pragma unroll
            for (int s4 = 0; s4 < 4; s4++)
                *(float4*)&Bv[s4 * 4] = *(const float4*)&Bs[t][s4 * 4];
            float dtx = dt * xv;
            dsum += dt;
#pragma unroll
            for (int s = 0; s < 16; s++)
                h[s] = fmaf(exp2f(dt * As2[s]), h[s], Bv[s] * dtx);
        }
    }

    size_t hb = (((size_t)b * NC + c) * DINNER + d) * 16;
#pragma unroll
    for (int s4 = 0; s4 < 4; s4++)
        *(float4*)&Hend[hb + s4 * 4] = *(float4*)&h[s4 * 4];
    dtsum[((size_t)b * NC + c) * DINNER + d] = dsum;
}

// ---------------------------------------------------------------------------
// carry: thread per (b,d,s); walk NC chunks; Hstart[c] = running state.
// ---------------------------------------------------------------------------
__global__ __launch_bounds__(256) void carry_kernel(const float* __restrict__ Hend,
                                                    const float* __restrict__ dtsum,
                                                    const float* __restrict__ A_log,
                                                    float* __restrict__ Hstart)
{
    const int idx = blockIdx.x * 256 + threadIdx.x;   // (b,d,s)
    const int s = idx & 15;
    const int d = (idx >> 4) & (DINNER - 1);
    const int b = idx >> 15;
    const float As2 = -__expf(A_log[d * 16 + s]) * 1.44269504f;
    float hs = 0.f;
    for (int c = 0; c < NC; c++) {
        size_t off = ((size_t)b * NC + c);
        float P  = exp2f(As2 * dtsum[off * DINNER + d]);
        size_t hi = (off * DINNER + d) * 16 + s;
        float he = Hend[hi];
        Hstart[hi] = hs;
        hs = fmaf(P, hs, he);
    }
}

// ---------------------------------------------------------------------------
// scan3: thread-per-d, h_start from carry. y(+D*x) overwrites xs[t] in place
// (each wave only touches its own 64 columns). Fused z-gate epilogue -> bf16.
// ---------------------------------------------------------------------------
__global__ __launch_bounds__(256) void scan3_kernel(const float* __restrict__ xb,
                                                    const float* __restrict__ dtraw,
                                                    const float* __restrict__ Btb,
                                                    const float* __restrict__ Ctb,
                                                    const float* __restrict__ A_log,
                                                    const float* __restrict__ dtw,
                                                    const float* __restrict__ dtb,
                                                    const float* __restrict__ Hstart,
                                                    const float* __restrict__ xz,
                                                    const float* __restrict__ Dp,
                                                    ushort_t* __restrict__ ygb)
{
    __shared__ float raw[LC];
    __shared__ float xs[LC][256];
    __shared__ float Bs[LC][16];
    __shared__ float Cs[LC][16];

    const int tid = threadIdx.x;
    const int c   = blockIdx.x;
    const int b   = blockIdx.z;
    const int d0  = blockIdx.y * 256;
    const int d   = d0 + tid;
    const int t0  = c * LC;

    if (tid < LC / 4)
        *(float4*)&raw[tid * 4] = *(const float4*)&dtraw[b * SEQ + t0 + tid * 4];
    if (tid < 128)
        *(float4*)&Bs[0][tid * 4] = *(const float4*)&Btb[((size_t)b * SEQ + t0) * 16 + tid * 4];
    else {
        int u = tid - 128;
        *(float4*)&Cs[0][u * 4] = *(const float4*)&Ctb[((size_t)b * SEQ + t0) * 16 + u * 4];
    }
#pragma unroll
    for (int j = 0; j < 8; j++) {
        int e = j * 256 + tid;
        int rr = e >> 6, c4 = (e & 63) * 4;
        *(float4*)&xs[rr][c4] = *(const float4*)&xb[((size_t)b * SEQ + t0 + rr) * DINNER + d0 + c4];
    }

    const float wd = dtw[d], bd = dtb[d];
    const float Dd = Dp[d];
    const float As2_0 = -__expf(A_log[d * 16]) * 1.44269504f;
    const bool fast = a_structure_ok(A_log, d, As2_0);

    float h[16];
    {
        size_t hb = (((size_t)b * NC + c) * DINNER + d) * 16;
#pragma unroll
        for (int s4 = 0; s4 < 4; s4++)
            *(float4*)&h[s4 * 4] = *(const float4*)&Hstart[hb + s4 * 4];
    }
    __syncthreads();

    if (fast) {
#pragma unroll 2
        for (int t = 0; t < LC; t++) {
            float dt = softplusf(fmaf(raw[t], wd, bd));
            float xv = xs[t][tid];
            float Bv[16], Cv[16];
#pragma unroll
            for (int s4 = 0; s4 < 4; s4++) {
                *(float4*)&Bv[s4 * 4] = *(const float4*)&Bs[t][s4 * 4];
                *(float4*)&Cv[s4 * 4] = *(const float4*)&Cs[t][s4 * 4];
            }
            float a[16];
            qpowers(exp2f(dt * As2_0), a);
            float dtx = dt * xv;
            float acc = 0.f;
#pragma unroll
            for (int s = 0; s < 16; s++) {
                h[s] = fmaf(a[s], h[s], Bv[s] * dtx);
                acc = fmaf(h[s], Cv[s], acc);
            }
            xs[t][tid] = fmaf(Dd, xv, acc);   // in-place y (own column)
        }
    } else {
        float As2[16];
#pragma unroll
        for (int s = 0; s < 16; s++)
            As2[s] = -__expf(A_log[d * 16 + s]) * 1.44269504f;
#pragma unroll 2
        for (int t = 0; t < LC; t++) {
            float dt = softplusf(fmaf(raw[t], wd, bd));
            float xv = xs[t][tid];
            float Bv[16], Cv[16];
#pragma unroll
            for (int s4 = 0; s4 < 4; s4++) {
                *(float4*)&Bv[s4 * 4] = *(const float4*)&Bs[t][s4 * 4];
                *(float4*)&Cv[s4 * 4] = *(const float4*)&Cs[t][s4 * 4];
            }
            float dtx = dt * xv;
            float acc = 0.f;
#pragma unroll
            for (int s = 0; s < 16; s++) {
                h[s] = fmaf(exp2f(dt * As2[s]), h[s], Bv[s] * dtx);
                acc = fmaf(h[s], Cv[s], acc);
            }
            xs[t][tid] = fmaf(Dd, xv, acc);
        }
    }
    __syncthreads();

    // z-gate epilogue: ygb = (y) * silu(z), bf16, coalesced
#pragma unroll
    for (int j = 0; j < 8; j++) {
        int e = j * 256 + tid;
        int rr = e >> 6, c4 = (e & 63) * 4;
        float4 yv = *(const float4*)&xs[rr][c4];
        float4 zv = *(const float4*)&xz[((size_t)b * SEQ + t0 + rr) * (2 * DINNER) + DINNER + d0 + c4];
        ushort4 u;
        u.x = f2bf(yv.x * (zv.x / (1.f + __expf(-zv.x))));
        u.y = f2bf(yv.y * (zv.y / (1.f + __expf(-zv.y))));
        u.z = f2bf(yv.z * (zv.z / (1.f + __expf(-zv.z))));
        u.w = f2bf(yv.w * (zv.w / (1.f + __expf(-zv.w))));
        *(ushort4*)&ygb[((size_t)b * SEQ + t0 + rr) * DINNER + d0 + c4] = u;
    }
}

// ---------------------------------------------------------------------------
extern "C" void kernel_launch(void* const* d_in, const int* in_sizes, int n_in,
                              void* d_out, int out_size, void* d_ws, size_t ws_size,
                              hipStream_t stream)
{
    const float* x         = (const float*)d_in[0];
    const float* in_proj_w = (const float*)d_in[1];
    const float* conv_w    = (const float*)d_in[2];
    const float* conv_b    = (const float*)d_in[3];
    const float* x_proj_w  = (const float*)d_in[4];
    const float* dt_proj_w = (const float*)d_in[5];
    const float* dt_proj_b = (const float*)d_in[6];
    const float* A_log     = (const float*)d_in[7];
    const float* D_param   = (const float*)d_in[8];
    const float* c_proj_w  = (const float*)d_in[9];
    float* out = (float*)d_out;

    float* ws    = (float*)d_ws;
    float* xz    = ws;                                   // BT*4096 f32
    float* xb    = xz  + (size_t)BT * 4096;              // BT*2048 f32
    float* Btb   = xb  + (size_t)BT * DINNER;            // BT*16
    float* Ctb   = Btb + (size_t)BT * 16;                // BT*16
    float* dtraw = Ctb + (size_t)BT * 16;                // BT (B,C,dt contiguous BT*33)
    float* Hend  = dtraw + BT;                           // B*NC*D*16 = 2M f32
    float* Hstart= Hend + (size_t)BATCH * NC * DINNER * 16;
    float* dtsum = Hstart + (size_t)BATCH * NC * DINNER * 16; // B*NC*D
    ushort_t* xbf = (ushort_t*)(dtsum + (size_t)BATCH * NC * DINNER);
    ushort_t* w1T = xbf + (size_t)BT * DMODEL;           // 4096*1024 bf16
    ushort_t* w2T = w1T + (size_t)(2 * DINNER) * DMODEL; // 1024*2048 bf16
    ushort_t* ygb = w2T + (size_t)DMODEL * DINNER;       // BT*2048 bf16

    // zero B/C/dtraw accumulators (BT*33 = 67584 floats)
    zero_kernel<<<dim3(66), 256, 0, stream>>>(Btb);

    cast_bf16_kernel<<<dim3((BT * DMODEL) / (8 * 256)), 256, 0, stream>>>(x, xbf);
    transpose_cast_kernel<<<dim3((2 * DINNER) / 32, DMODEL / 32), 256, 0, stream>>>(
        in_proj_w, w1T, DMODEL, 2 * DINNER);
    transpose_cast_kernel<<<dim3(DMODEL / 32, DINNER / 32), 256, 0, stream>>>(
        c_proj_w, w2T, DINNER, DMODEL);

    // 1. xz = x @ in_proj_w (bf16 MFMA)
    gemm_bt<128, 128><<<dim3((2 * DINNER) / 128, BT / 128), 256, 0, stream>>>(
        xbf, w1T, xz, BT, 2 * DINNER, DMODEL);

    // 2. conv + bias + silu
    conv_silu_kernel<<<dim3(SEQ / 64, DINNER / 64, BATCH), 256, 0, stream>>>(
        xz, conv_w, conv_b, xb);

    // 3. x_ssm projection (split-K atomics)
    xproj_kernel<<<dim3(BT / 8, 8), 256, 0, stream>>>(xb, x_proj_w, Btb, Ctb, dtraw);

    // 4. chunked scan: local -> carry -> final(+fused gate, bf16 out)
    scan1_kernel<<<dim3(NC, DINNER / 256, BATCH), 256, 0, stream>>>(
        xb, dtraw, Btb, A_log, dt_proj_w, dt_proj_b, Hend, dtsum);
    carry_kernel<<<dim3(BATCH * DINNER * 16 / 256), 256, 0, stream>>>(
        Hend, dtsum, A_log, Hstart);
    scan3_kernel<<<dim3(NC, DINNER / 256, BATCH), 256, 0, stream>>>(
        xb, dtraw, Btb, Ctb, A_log, dt_proj_w, dt_proj_b, Hstart, xz, D_param, ygb);

    // 5. out = y @ c_proj_w (bf16 MFMA)
    gemm_bt<64, 128><<<dim3(DMODEL / 128, BT / 64), 256, 0, stream>>>(
        ygb, w2T, out, BT, DMODEL, DINNER);
}

// Round 7
// 173.280 us; speedup vs baseline: 1.3219x; 1.0147x over previous
//
#include <hip/hip_runtime.h>
#include <math.h>

#define DMODEL 1024
#define DSTATE 16
#define DCONV 4
#define DINNER 2048
#define BATCH 2
#define SEQ 1024
#define BT (BATCH*SEQ)   // 2048
#define NC 32            // scan chunks
#define LC 32            // steps per chunk (NC*LC == SEQ)

typedef unsigned short ushort_t;
typedef __attribute__((ext_vector_type(8))) short short8;
typedef __attribute__((ext_vector_type(4))) float f32x4;

__device__ __forceinline__ ushort_t f2bf(float f) {
    union { float f; unsigned int u; } v; v.f = f;
    unsigned int r = v.u + 0x7fffu + ((v.u >> 16) & 1u);
    return (ushort_t)(r >> 16);
}

__device__ __forceinline__ float softplusf(float x) {
    return (x > 20.f) ? x : log1pf(__expf(x));
}

#define GLOAD_LDS16(G, L) \
  __builtin_amdgcn_global_load_lds((const __attribute__((address_space(1))) void*)(G), \
                                   (__attribute__((address_space(3))) void*)(L), 16, 0, 0)

// ---------------------------------------------------------------------------
// cast fp32 -> bf16 (x -> xbf); first 66 blocks also zero the B/C/dtraw
// accumulator region (BT*33 floats) used by xproj's atomics.
// ---------------------------------------------------------------------------
__global__ __launch_bounds__(256) void cast_bf16_kernel(const float* __restrict__ in,
                                                        ushort_t* __restrict__ out,
                                                        float* __restrict__ zp)
{
    size_t i = ((size_t)blockIdx.x * 256 + threadIdx.x) * 8;
    float4 a = *(const float4*)&in[i];
    float4 b = *(const float4*)&in[i + 4];
    uint4 p;
    p.x = (unsigned)f2bf(a.x) | ((unsigned)f2bf(a.y) << 16);
    p.y = (unsigned)f2bf(a.z) | ((unsigned)f2bf(a.w) << 16);
    p.z = (unsigned)f2bf(b.x) | ((unsigned)f2bf(b.y) << 16);
    p.w = (unsigned)f2bf(b.z) | ((unsigned)f2bf(b.w) << 16);
    *(uint4*)&out[i] = p;
    if (blockIdx.x < 66) {
        size_t z = ((size_t)blockIdx.x * 256 + threadIdx.x) * 4;
        *(float4*)&zp[z] = make_float4(0.f, 0.f, 0.f, 0.f);
    }
}

// ---------------------------------------------------------------------------
__global__ __launch_bounds__(256) void transpose_cast_kernel(const float* __restrict__ in,
                                                             ushort_t* __restrict__ out,
                                                             int R, int Cc)
{
    __shared__ float t[32][33];
    const int r0 = blockIdx.y * 32;
    const int c0 = blockIdx.x * 32;
    const int tid = threadIdx.x;
    {
        int lr = tid >> 3, lc4 = (tid & 7) * 4;
        float4 v = *(const float4*)&in[(size_t)(r0 + lr) * Cc + c0 + lc4];
        t[lr][lc4 + 0] = v.x; t[lr][lc4 + 1] = v.y;
        t[lr][lc4 + 2] = v.z; t[lr][lc4 + 3] = v.w;
    }
    __syncthreads();
    {
        int oc = tid >> 3, rq = (tid & 7) * 4;
        ushort4 u;
        u.x = f2bf(t[rq + 0][oc]);
        u.y = f2bf(t[rq + 1][oc]);
        u.z = f2bf(t[rq + 2][oc]);
        u.w = f2bf(t[rq + 3][oc]);
        *(ushort4*)&out[(size_t)(c0 + oc) * R + r0 + rq] = u;
    }
}

// ---------------------------------------------------------------------------
// bf16 MFMA GEMM: C[M][N] (fp32) = A[M][K] @ Bt[N][K]^T. BK=64, 2 k-halves
// per K-step (half the barriers of BK=32 per MFMA).
// ---------------------------------------------------------------------------
template<int BM, int BN>
__global__ __launch_bounds__(256) void gemm_bt(const ushort_t* __restrict__ A,
                                               const ushort_t* __restrict__ Bt,
                                               float* __restrict__ C,
                                               int M, int N, int K)
{
    constexpr int BK = 64;
    constexpr int AL = BM * BK / (256 * 8);   // gload_lds16 per thread (A)
    constexpr int BL = BN * BK / (256 * 8);
    constexpr int FM = BM / 32;
    constexpr int FN = BN / 32;
    __shared__ __align__(16) ushort_t Al[BM * BK];
    __shared__ __align__(16) ushort_t Bl[BN * BK];

    const int tid  = threadIdx.x;
    const int lane = tid & 63;
    const int wid  = tid >> 6;
    const int wr   = wid >> 1;
    const int wc   = wid & 1;
    const int bm   = blockIdx.y * BM;
    const int bn   = blockIdx.x * BN;

    f32x4 acc[FM][FN] = {};

    for (int k0 = 0; k0 < K; k0 += BK) {
        // stage A/B tiles: row-major [.][64] bf16; chunk c -> byte off c*16
#pragma unroll
        for (int j = 0; j < AL; j++) {
            int chunk = j * 256 + tid;
            GLOAD_LDS16(&A[(size_t)(bm + (chunk >> 3)) * K + k0 + (chunk & 7) * 8],
                        &Al[(size_t)(j * 256 + wid * 64) * 8]);
        }
#pragma unroll
        for (int j = 0; j < BL; j++) {
            int chunk = j * 256 + tid;
            GLOAD_LDS16(&Bt[(size_t)(bn + (chunk >> 3)) * K + k0 + (chunk & 7) * 8],
                        &Bl[(size_t)(j * 256 + wid * 64) * 8]);
        }
        __syncthreads();

#pragma unroll
        for (int kk = 0; kk < 2; kk++) {
            short8 af[FM], bf[FN];
#pragma unroll
            for (int m = 0; m < FM; m++)
                af[m] = *(const short8*)&Al[(wr * (BM / 2) + m * 16 + (lane & 15)) * BK
                                            + (lane >> 4) * 8 + kk * 32];
#pragma unroll
            for (int n = 0; n < FN; n++)
                bf[n] = *(const short8*)&Bl[(wc * (BN / 2) + n * 16 + (lane & 15)) * BK
                                            + (lane >> 4) * 8 + kk * 32];
#pragma unroll
            for (int m = 0; m < FM; m++)
#pragma unroll
                for (int n = 0; n < FN; n++)
                    acc[m][n] = __builtin_amdgcn_mfma_f32_16x16x32_bf16(af[m], bf[n], acc[m][n], 0, 0, 0);
        }
        __syncthreads();
    }

#pragma unroll
    for (int m = 0; m < FM; m++)
#pragma unroll
        for (int n = 0; n < FN; n++) {
            int row0 = bm + wr * (BM / 2) + m * 16 + (lane >> 4) * 4;
            int col  = bn + wc * (BN / 2) + n * 16 + (lane & 15);
#pragma unroll
            for (int r = 0; r < 4; r++)
                C[(size_t)(row0 + r) * N + col] = acc[m][n][r];
        }
}

// ---------------------------------------------------------------------------
// Depthwise causal conv(4) + bias + SiLU, row-major out.
// ---------------------------------------------------------------------------
__global__ __launch_bounds__(256) void conv_silu_kernel(const float* __restrict__ xz,
                                                        const float* __restrict__ cw,
                                                        const float* __restrict__ cb,
                                                        float* __restrict__ xb_rm)
{
    __shared__ float tile[64 + 3][64];
    const int b  = blockIdx.z;
    const int t0 = blockIdx.x * 64;
    const int d0 = blockIdx.y * 64;
    const int tid = threadIdx.x;

    for (int e = tid; e < 67 * 16; e += 256) {
        int r  = e / 16;
        int c4 = (e % 16) * 4;
        int t  = t0 - 3 + r;
        float4 v = make_float4(0.f, 0.f, 0.f, 0.f);
        if (t >= 0)
            v = *(const float4*)&xz[((size_t)b * SEQ + t) * (2 * DINNER) + d0 + c4];
        *(float4*)&tile[r][c4] = v;
    }
    __syncthreads();

    const int dl = tid & 63;
    const int tb = tid >> 6;
    const int d  = d0 + dl;
    const float w0 = cw[d * 4 + 0], w1 = cw[d * 4 + 1];
    const float w2 = cw[d * 4 + 2], w3 = cw[d * 4 + 3];
    const float bias = cb[d];

#pragma unroll
    for (int ii = 0; ii < 16; ii++) {
        int tl = tb + 4 * ii;
        float s = bias;
        s = fmaf(tile[tl + 0][dl], w0, s);
        s = fmaf(tile[tl + 1][dl], w1, s);
        s = fmaf(tile[tl + 2][dl], w2, s);
        s = fmaf(tile[tl + 3][dl], w3, s);
        float sil = s / (1.f + __expf(-s));
        xb_rm[((size_t)b * SEQ + t0 + tl) * DINNER + d] = sil;
    }
}

// ---------------------------------------------------------------------------
// xproj split-K: grid (BT/8, 8); stages xs + ws in LDS; atomics out.
// ---------------------------------------------------------------------------
__global__ __launch_bounds__(256) void xproj_kernel(const float* __restrict__ xb,
                                                    const float* __restrict__ w,
                                                    float* __restrict__ Btb,
                                                    float* __restrict__ Ctb,
                                                    float* __restrict__ dtraw)
{
    __shared__ float xs[8][256];
    __shared__ float ws[256][33];
    const int bt0 = blockIdx.x * 8;
    const int kc  = blockIdx.y * 256;
    const int tid = threadIdx.x;
    const int r = tid >> 5, n = tid & 31;

#pragma unroll
    for (int j = 0; j < 2; j++) {
        int e4 = (j * 256 + tid) * 4;
        int rr = e4 >> 8, cc = e4 & 255;
        *(float4*)&xs[rr][cc] = *(const float4*)&xb[(size_t)(bt0 + rr) * DINNER + kc + cc];
    }
    {
        const float* wsrc = w + (size_t)kc * 33;
        float* wdst = &ws[0][0];
        for (int e4 = tid; e4 < 2112; e4 += 256)
            *(float4*)&wdst[e4 * 4] = *(const float4*)&wsrc[e4 * 4];
    }
    __syncthreads();

    float acc = 0.f;
#pragma unroll 16
    for (int kk = 0; kk < 256; kk += 4) {
        float4 xv = *(const float4*)&xs[r][kk];
        acc = fmaf(xv.x, ws[kk + 0][n], acc);
        acc = fmaf(xv.y, ws[kk + 1][n], acc);
        acc = fmaf(xv.z, ws[kk + 2][n], acc);
        acc = fmaf(xv.w, ws[kk + 3][n], acc);
    }
    float dacc = 0.f;
#pragma unroll
    for (int j = 0; j < 8; j++)
        dacc = fmaf(xs[r][n * 8 + j], ws[n * 8 + j][32], dacc);
#pragma unroll
    for (int off = 16; off; off >>= 1)
        dacc += __shfl_xor(dacc, off, 32);

    if (n < 16) atomicAdd(&Btb[(bt0 + r) * 16 + n], acc);
    else        atomicAdd(&Ctb[(bt0 + r) * 16 + (n - 16)], acc);
    if (n == 0) atomicAdd(&dtraw[bt0 + r], dacc);
}

// ---------------------------------------------------------------------------
// Power-tree: a[s] = q^(s+1) for s=0..15 (binary decomposition, depth ~4).
// ---------------------------------------------------------------------------
__device__ __forceinline__ void qpowers(float q, float* a)
{
    float q2 = q * q, q4 = q2 * q2, q8 = q4 * q4;
    a[0] = q;        a[1] = q2;       a[2] = q2 * q;   a[3] = q4;
    a[4] = q4 * q;   a[5] = q4 * q2;  a[6] = q4 * a[2];a[7] = q8;
    a[8] = q8 * q;   a[9] = q8 * q2;  a[10]= q8 * a[2];a[11]= q8 * q4;
    a[12]= q8 * a[4];a[13]= q8 * a[5];a[14]= q8 * a[6];a[15]= q8 * q8;
}

// Check A_log structure: As2[s] == (s+1)*As2[0] (fast path validity).
__device__ __forceinline__ bool a_structure_ok(const float* A_log, int d, float As2_0)
{
    bool ok = true;
#pragma unroll
    for (int s = 1; s < 16; s++) {
        float v = -__expf(A_log[d * 16 + s]) * 1.44269504f;
        ok &= (fabsf(v - (float)(s + 1) * As2_0) <= 1e-4f * (float)(s + 1) * fabsf(As2_0));
    }
    return ok;
}

// ---------------------------------------------------------------------------
// scan1: thread-per-d. Block = 256 d x one chunk of LC=32 steps.
// ---------------------------------------------------------------------------
__global__ __launch_bounds__(256) void scan1_kernel(const float* __restrict__ xb,
                                                    const float* __restrict__ dtraw,
                                                    const float* __restrict__ Btb,
                                                    const float* __restrict__ A_log,
                                                    const float* __restrict__ dtw,
                                                    const float* __restrict__ dtb,
                                                    float* __restrict__ Hend,
                                                    float* __restrict__ dtsum)
{
    __shared__ float raw[LC];
    __shared__ float xs[LC][256];
    __shared__ float Bs[LC][16];

    const int tid = threadIdx.x;
    const int c   = blockIdx.x;
    const int b   = blockIdx.z;
    const int d0  = blockIdx.y * 256;
    const int d   = d0 + tid;
    const int t0  = c * LC;

    if (tid < LC / 4)
        *(float4*)&raw[tid * 4] = *(const float4*)&dtraw[b * SEQ + t0 + tid * 4];
    if (tid < 128)
        *(float4*)&Bs[0][tid * 4] = *(const float4*)&Btb[((size_t)b * SEQ + t0) * 16 + tid * 4];
#pragma unroll
    for (int j = 0; j < 8; j++) {
        int e = j * 256 + tid;
        int rr = e >> 6, c4 = (e & 63) * 4;
        *(float4*)&xs[rr][c4] = *(const float4*)&xb[((size_t)b * SEQ + t0 + rr) * DINNER + d0 + c4];
    }

    const float wd = dtw[d], bd = dtb[d];
    const float As2_0 = -__expf(A_log[d * 16]) * 1.44269504f;
    const bool fast = a_structure_ok(A_log, d, As2_0);

    float h[16];
#pragma unroll
    for (int s = 0; s < 16; s++) h[s] = 0.f;
    float dsum = 0.f;
    __syncthreads();

    if (fast) {
#pragma unroll 2
        for (int t = 0; t < LC; t++) {
            float dt = softplusf(fmaf(raw[t], wd, bd));
            float xv = xs[t][tid];
            float Bv[16];
#pragma unroll
            for (int s4 = 0; s4 < 4; s4++)
                *(float4*)&Bv[s4 * 4] = *(const float4*)&Bs[t][s4 * 4];
            float a[16];
            qpowers(exp2f(dt * As2_0), a);
            float dtx = dt * xv;
            dsum += dt;
#pragma unroll
            for (int s = 0; s < 16; s++)
                h[s] = fmaf(a[s], h[s], Bv[s] * dtx);
        }
    } else {
        float As2[16];
#pragma unroll
        for (int s = 0; s < 16; s++)
            As2[s] = -__expf(A_log[d * 16 + s]) * 1.44269504f;
#pragma unroll 2
        for (int t = 0; t < LC; t++) {
            float dt = softplusf(fmaf(raw[t], wd, bd));
            float xv = xs[t][tid];
            float Bv[16];
#pragma unroll
            for (int s4 = 0; s4 < 4; s4++)
                *(float4*)&Bv[s4 * 4] = *(const float4*)&Bs[t][s4 * 4];
            float dtx = dt * xv;
            dsum += dt;
#pragma unroll
            for (int s = 0; s < 16; s++)
                h[s] = fmaf(exp2f(dt * As2[s]), h[s], Bv[s] * dtx);
        }
    }

    size_t hb = (((size_t)b * NC + c) * DINNER + d) * 16;
#pragma unroll
    for (int s4 = 0; s4 < 4; s4++)
        *(float4*)&Hend[hb + s4 * 4] = *(float4*)&h[s4 * 4];
    dtsum[((size_t)b * NC + c) * DINNER + d] = dsum;
}

// ---------------------------------------------------------------------------
// carry: thread per (b,d,s); walk NC chunks; Hstart[c] = running state.
// ---------------------------------------------------------------------------
__global__ __launch_bounds__(256) void carry_kernel(const float* __restrict__ Hend,
                                                    const float* __restrict__ dtsum,
                                                    const float* __restrict__ A_log,
                                                    float* __restrict__ Hstart)
{
    const int idx = blockIdx.x * 256 + threadIdx.x;   // (b,d,s)
    const int s = idx & 15;
    const int d = (idx >> 4) & (DINNER - 1);
    const int b = idx >> 15;
    const float As2 = -__expf(A_log[d * 16 + s]) * 1.44269504f;
    float hs = 0.f;
    for (int c = 0; c < NC; c++) {
        size_t off = ((size_t)b * NC + c);
        float P  = exp2f(As2 * dtsum[off * DINNER + d]);
        size_t hi = (off * DINNER + d) * 16 + s;
        float he = Hend[hi];
        Hstart[hi] = hs;
        hs = fmaf(P, hs, he);
    }
}

// ---------------------------------------------------------------------------
// scan3: thread-per-d, h_start from carry; in-place y; fused z-gate -> bf16.
// ---------------------------------------------------------------------------
__global__ __launch_bounds__(256) void scan3_kernel(const float* __restrict__ xb,
                                                    const float* __restrict__ dtraw,
                                                    const float* __restrict__ Btb,
                                                    const float* __restrict__ Ctb,
                                                    const float* __restrict__ A_log,
                                                    const float* __restrict__ dtw,
                                                    const float* __restrict__ dtb,
                                                    const float* __restrict__ Hstart,
                                                    const float* __restrict__ xz,
                                                    const float* __restrict__ Dp,
                                                    ushort_t* __restrict__ ygb)
{
    __shared__ float raw[LC];
    __shared__ float xs[LC][256];
    __shared__ float Bs[LC][16];
    __shared__ float Cs[LC][16];

    const int tid = threadIdx.x;
    const int c   = blockIdx.x;
    const int b   = blockIdx.z;
    const int d0  = blockIdx.y * 256;
    const int d   = d0 + tid;
    const int t0  = c * LC;

    if (tid < LC / 4)
        *(float4*)&raw[tid * 4] = *(const float4*)&dtraw[b * SEQ + t0 + tid * 4];
    if (tid < 128)
        *(float4*)&Bs[0][tid * 4] = *(const float4*)&Btb[((size_t)b * SEQ + t0) * 16 + tid * 4];
    else {
        int u = tid - 128;
        *(float4*)&Cs[0][u * 4] = *(const float4*)&Ctb[((size_t)b * SEQ + t0) * 16 + u * 4];
    }
#pragma unroll
    for (int j = 0; j < 8; j++) {
        int e = j * 256 + tid;
        int rr = e >> 6, c4 = (e & 63) * 4;
        *(float4*)&xs[rr][c4] = *(const float4*)&xb[((size_t)b * SEQ + t0 + rr) * DINNER + d0 + c4];
    }

    const float wd = dtw[d], bd = dtb[d];
    const float Dd = Dp[d];
    const float As2_0 = -__expf(A_log[d * 16]) * 1.44269504f;
    const bool fast = a_structure_ok(A_log, d, As2_0);

    float h[16];
    {
        size_t hb = (((size_t)b * NC + c) * DINNER + d) * 16;
#pragma unroll
        for (int s4 = 0; s4 < 4; s4++)
            *(float4*)&h[s4 * 4] = *(const float4*)&Hstart[hb + s4 * 4];
    }
    __syncthreads();

    if (fast) {
#pragma unroll 2
        for (int t = 0; t < LC; t++) {
            float dt = softplusf(fmaf(raw[t], wd, bd));
            float xv = xs[t][tid];
            float Bv[16], Cv[16];
#pragma unroll
            for (int s4 = 0; s4 < 4; s4++) {
                *(float4*)&Bv[s4 * 4] = *(const float4*)&Bs[t][s4 * 4];
                *(float4*)&Cv[s4 * 4] = *(const float4*)&Cs[t][s4 * 4];
            }
            float a[16];
            qpowers(exp2f(dt * As2_0), a);
            float dtx = dt * xv;
            float acc = 0.f;
#pragma unroll
            for (int s = 0; s < 16; s++) {
                h[s] = fmaf(a[s], h[s], Bv[s] * dtx);
                acc = fmaf(h[s], Cv[s], acc);
            }
            xs[t][tid] = fmaf(Dd, xv, acc);   // in-place y (own column)
        }
    } else {
        float As2[16];
#pragma unroll
        for (int s = 0; s < 16; s++)
            As2[s] = -__expf(A_log[d * 16 + s]) * 1.44269504f;
#pragma unroll 2
        for (int t = 0; t < LC; t++) {
            float dt = softplusf(fmaf(raw[t], wd, bd));
            float xv = xs[t][tid];
            float Bv[16], Cv[16];
#pragma unroll
            for (int s4 = 0; s4 < 4; s4++) {
                *(float4*)&Bv[s4 * 4] = *(const float4*)&Bs[t][s4 * 4];
                *(float4*)&Cv[s4 * 4] = *(const float4*)&Cs[t][s4 * 4];
            }
            float dtx = dt * xv;
            float acc = 0.f;
#pragma unroll
            for (int s = 0; s < 16; s++) {
                h[s] = fmaf(exp2f(dt * As2[s]), h[s], Bv[s] * dtx);
                acc = fmaf(h[s], Cv[s], acc);
            }
            xs[t][tid] = fmaf(Dd, xv, acc);
        }
    }
    __syncthreads();

    // z-gate epilogue: ygb = y * silu(z), bf16, coalesced
#pragma unroll
    for (int j = 0; j < 8; j++) {
        int e = j * 256 + tid;
        int rr = e >> 6, c4 = (e & 63) * 4;
        float4 yv = *(const float4*)&xs[rr][c4];
        float4 zv = *(const float4*)&xz[((size_t)b * SEQ + t0 + rr) * (2 * DINNER) + DINNER + d0 + c4];
        ushort4 u;
        u.x = f2bf(yv.x * (zv.x / (1.f + __expf(-zv.x))));
        u.y = f2bf(yv.y * (zv.y / (1.f + __expf(-zv.y))));
        u.z = f2bf(yv.z * (zv.z / (1.f + __expf(-zv.z))));
        u.w = f2bf(yv.w * (zv.w / (1.f + __expf(-zv.w))));
        *(ushort4*)&ygb[((size_t)b * SEQ + t0 + rr) * DINNER + d0 + c4] = u;
    }
}

// ---------------------------------------------------------------------------
extern "C" void kernel_launch(void* const* d_in, const int* in_sizes, int n_in,
                              void* d_out, int out_size, void* d_ws, size_t ws_size,
                              hipStream_t stream)
{
    const float* x         = (const float*)d_in[0];
    const float* in_proj_w = (const float*)d_in[1];
    const float* conv_w    = (const float*)d_in[2];
    const float* conv_b    = (const float*)d_in[3];
    const float* x_proj_w  = (const float*)d_in[4];
    const float* dt_proj_w = (const float*)d_in[5];
    const float* dt_proj_b = (const float*)d_in[6];
    const float* A_log     = (const float*)d_in[7];
    const float* D_param   = (const float*)d_in[8];
    const float* c_proj_w  = (const float*)d_in[9];
    float* out = (float*)d_out;

    float* ws    = (float*)d_ws;
    float* xz    = ws;                                   // BT*4096 f32
    float* xb    = xz  + (size_t)BT * 4096;              // BT*2048 f32
    float* Btb   = xb  + (size_t)BT * DINNER;            // BT*16
    float* Ctb   = Btb + (size_t)BT * 16;                // BT*16
    float* dtraw = Ctb + (size_t)BT * 16;                // BT (B,C,dt contiguous BT*33)
    float* Hend  = dtraw + BT;                           // B*NC*D*16
    float* Hstart= Hend + (size_t)BATCH * NC * DINNER * 16;
    float* dtsum = Hstart + (size_t)BATCH * NC * DINNER * 16; // B*NC*D
    ushort_t* xbf = (ushort_t*)(dtsum + (size_t)BATCH * NC * DINNER);
    ushort_t* w1T = xbf + (size_t)BT * DMODEL;           // 4096*1024 bf16
    ushort_t* w2T = w1T + (size_t)(2 * DINNER) * DMODEL; // 1024*2048 bf16
    ushort_t* ygb = w2T + (size_t)DMODEL * DINNER;       // BT*2048 bf16

    // cast x -> bf16 (also zeroes B/C/dtraw accumulators in first 66 blocks)
    cast_bf16_kernel<<<dim3((BT * DMODEL) / (8 * 256)), 256, 0, stream>>>(x, xbf, Btb);
    transpose_cast_kernel<<<dim3((2 * DINNER) / 32, DMODEL / 32), 256, 0, stream>>>(
        in_proj_w, w1T, DMODEL, 2 * DINNER);
    transpose_cast_kernel<<<dim3(DMODEL / 32, DINNER / 32), 256, 0, stream>>>(
        c_proj_w, w2T, DINNER, DMODEL);

    // 1. xz = x @ in_proj_w (bf16 MFMA, BK=64)
    gemm_bt<128, 128><<<dim3((2 * DINNER) / 128, BT / 128), 256, 0, stream>>>(
        xbf, w1T, xz, BT, 2 * DINNER, DMODEL);

    // 2. conv + bias + silu
    conv_silu_kernel<<<dim3(SEQ / 64, DINNER / 64, BATCH), 256, 0, stream>>>(
        xz, conv_w, conv_b, xb);

    // 3. x_ssm projection (split-K atomics)
    xproj_kernel<<<dim3(BT / 8, 8), 256, 0, stream>>>(xb, x_proj_w, Btb, Ctb, dtraw);

    // 4. chunked scan: local -> carry -> final(+fused gate, bf16 out)
    scan1_kernel<<<dim3(NC, DINNER / 256, BATCH), 256, 0, stream>>>(
        xb, dtraw, Btb, A_log, dt_proj_w, dt_proj_b, Hend, dtsum);
    carry_kernel<<<dim3(BATCH * DINNER * 16 / 256), 256, 0, stream>>>(
        Hend, dtsum, A_log, Hstart);
    scan3_kernel<<<dim3(NC, DINNER / 256, BATCH), 256, 0, stream>>>(
        xb, dtraw, Btb, Ctb, A_log, dt_proj_w, dt_proj_b, Hstart, xz, D_param, ygb);

    // 5. out = y @ c_proj_w (bf16 MFMA, BK=64)
    gemm_bt<64, 128><<<dim3(DMODEL / 128, BT / 64), 256, 0, stream>>>(
        ygb, w2T, out, BT, DMODEL, DINNER);
}